// Round 1
// baseline (722.616 us; speedup 1.0000x reference)
//
#include <hip/hip_runtime.h>
#include <math.h>

#define N_NODES 100000
#define N_EDGES 1600000
#define IN_F 128
#define OUT_F 64
#define NEG_SLOPE 0.2f

#define SCAN_B 1024
#define NBLK ((N_NODES + SCAN_B - 1) / SCAN_B)   // 98

// ---- order-preserving float <-> unsigned key for atomicMax ----
__device__ __forceinline__ unsigned fkey(float f) {
    unsigned u = __float_as_uint(f);
    return (u & 0x80000000u) ? ~u : (u | 0x80000000u);
}
__device__ __forceinline__ float fdecode(unsigned k) {
    unsigned u = (k & 0x80000000u) ? (k ^ 0x80000000u) : ~k;
    return __uint_as_float(u);
}

__device__ __forceinline__ float wsum(float v) {
    #pragma unroll
    for (int off = 32; off; off >>= 1) v += __shfl_xor(v, off);
    return v;
}

// ---------------- Kernel A: h = feat @ W^T, fused el/er ----------------
// block = 256 (4 waves); each wave computes 4 nodes; lane = output feature.
// W cached in LDS (padded stride 132 floats -> 16B-aligned, conflict-spread).
__global__ __launch_bounds__(256) void k_gemm(
        const float* __restrict__ feat, const float* __restrict__ W,
        const float* __restrict__ attn_l, const float* __restrict__ attn_r,
        float* __restrict__ h, float* __restrict__ el, float* __restrict__ er) {
    __shared__ __align__(16) float wlds[OUT_F * 132];
    __shared__ __align__(16) float flds[4][4][IN_F];
    int tid = threadIdx.x;
    for (int i = tid; i < OUT_F * IN_F; i += 256)
        wlds[(i >> 7) * 132 + (i & 127)] = W[i];

    int wave = tid >> 6, lane = tid & 63;
    int wid = blockIdx.x * 4 + wave;   // 0..24999
    int n0  = wid * 4;                 // 4 consecutive nodes (N % 16 == 0)

    // stage 4 feat rows (128 float4) into this wave's LDS slab
    const float4* fsrc = (const float4*)(feat + (size_t)n0 * IN_F);
    float4* fdst = (float4*)(&flds[wave][0][0]);
    fdst[lane]      = fsrc[lane];
    fdst[lane + 64] = fsrc[lane + 64];
    __syncthreads();   // also covers the W load

    float acc0 = 0.f, acc1 = 0.f, acc2 = 0.f, acc3 = 0.f;
    #pragma unroll
    for (int k4 = 0; k4 < 32; ++k4) {
        float4 w  = *(const float4*)&wlds[lane * 132 + k4 * 4];
        float4 f0 = *(const float4*)&flds[wave][0][k4 * 4];
        float4 f1 = *(const float4*)&flds[wave][1][k4 * 4];
        float4 f2 = *(const float4*)&flds[wave][2][k4 * 4];
        float4 f3 = *(const float4*)&flds[wave][3][k4 * 4];
        acc0 += w.x * f0.x + w.y * f0.y + w.z * f0.z + w.w * f0.w;
        acc1 += w.x * f1.x + w.y * f1.y + w.z * f1.z + w.w * f1.w;
        acc2 += w.x * f2.x + w.y * f2.y + w.z * f2.z + w.w * f2.w;
        acc3 += w.x * f3.x + w.y * f3.y + w.z * f3.z + w.w * f3.w;
    }
    h[(size_t)(n0 + 0) * OUT_F + lane] = acc0;
    h[(size_t)(n0 + 1) * OUT_F + lane] = acc1;
    h[(size_t)(n0 + 2) * OUT_F + lane] = acc2;
    h[(size_t)(n0 + 3) * OUT_F + lane] = acc3;

    float al = attn_l[lane], ar = attn_r[lane];
    float l0 = wsum(acc0 * al), r0 = wsum(acc0 * ar);
    float l1 = wsum(acc1 * al), r1 = wsum(acc1 * ar);
    float l2 = wsum(acc2 * al), r2 = wsum(acc2 * ar);
    float l3 = wsum(acc3 * al), r3 = wsum(acc3 * ar);
    if (lane == 0) {
        el[n0 + 0] = l0; er[n0 + 0] = r0;
        el[n0 + 1] = l1; er[n0 + 1] = r1;
        el[n0 + 2] = l2; er[n0 + 2] = r2;
        el[n0 + 3] = l3; er[n0 + 3] = r3;
    }
}

// ---------------- init (ws is re-poisoned 0xAA every launch) ----------------
__global__ void k_init(unsigned* emax_u, float* denom, int* outdeg, int* indeg,
                       int* fill, int* rowstart) {
    int i = blockIdx.x * blockDim.x + threadIdx.x;
    if (i == 0) rowstart[N_NODES] = N_EDGES;
    if (i < N_NODES) {
        emax_u[i] = 0u;     // decodes to "-NaN" sentinel; only read if edges exist
        denom[i]  = 0.f;
        outdeg[i] = 0;
        indeg[i]  = 0;
        fill[i]   = 0;
    }
}

// ---------------- edge pass 1: leaky-relu score, degrees, segment max ----------------
__global__ void k_edge1(const int* __restrict__ src, const int* __restrict__ dst,
                        const float* __restrict__ el, const float* __restrict__ er,
                        float* __restrict__ eval, unsigned* emax_u,
                        int* outdeg, int* indeg) {
    int e = blockIdx.x * 256 + threadIdx.x;
    if (e >= N_EDGES) return;
    int s = src[e], d = dst[e];
    atomicAdd(&outdeg[s], 1);
    atomicAdd(&indeg[d], 1);
    float v = el[s] + er[d];
    v = (v > 0.f) ? v : NEG_SLOPE * v;
    eval[e] = v;
    atomicMax(&emax_u[d], fkey(v));
}

// ---------------- per-node: decode max, degree norms ----------------
__global__ void k_node(const unsigned* __restrict__ emax_u,
                       const int* __restrict__ outdeg, const int* __restrict__ indeg,
                       float* emax_f, float* onorm, float* innorm) {
    int i = blockIdx.x * blockDim.x + threadIdx.x;
    if (i >= N_NODES) return;
    emax_f[i] = fdecode(emax_u[i]);
    float od = (float)max(outdeg[i], 1);
    float id = (float)max(indeg[i], 1);
    onorm[i]  = 1.0f / sqrtf(od);
    innorm[i] = sqrtf(id);
}

// ---------------- edge pass 2: exp + segment-sum denom ----------------
__global__ void k_edge2(const int* __restrict__ dst, const float* __restrict__ emax_f,
                        float* __restrict__ eval, float* __restrict__ denom) {
    int e = blockIdx.x * 256 + threadIdx.x;
    if (e >= N_EDGES) return;
    int d = dst[e];
    float ee = expf(eval[e] - emax_f[d]);
    eval[e] = ee;
    atomicAdd(&denom[d], ee);
}

// ---------------- two-level exclusive scan of indeg -> rowstart ----------------
__global__ __launch_bounds__(SCAN_B) void k_scan1(const int* __restrict__ indeg, int* bsums) {
    __shared__ int s[SCAN_B];
    int t = threadIdx.x, i = blockIdx.x * SCAN_B + t;
    s[t] = (i < N_NODES) ? indeg[i] : 0;
    __syncthreads();
    for (int d = SCAN_B / 2; d; d >>= 1) {
        if (t < d) s[t] += s[t + d];
        __syncthreads();
    }
    if (t == 0) bsums[blockIdx.x] = s[0];
}

__global__ __launch_bounds__(128) void k_scan2(int* bsums) {
    __shared__ int s[128];
    int t = threadIdx.x;
    int v = (t < NBLK) ? bsums[t] : 0;
    s[t] = v;
    __syncthreads();
    for (int d = 1; d < 128; d <<= 1) {
        int add = (t >= d) ? s[t - d] : 0;
        __syncthreads();
        s[t] += add;
        __syncthreads();
    }
    if (t < NBLK) bsums[t] = s[t] - v;   // exclusive block offsets
}

__global__ __launch_bounds__(SCAN_B) void k_scan3(const int* __restrict__ indeg,
                                                  const int* __restrict__ bsums,
                                                  int* rowstart) {
    __shared__ int s[SCAN_B];
    int t = threadIdx.x, i = blockIdx.x * SCAN_B + t;
    int c = (i < N_NODES) ? indeg[i] : 0;
    s[t] = c;
    __syncthreads();
    for (int d = 1; d < SCAN_B; d <<= 1) {
        int add = (t >= d) ? s[t - d] : 0;
        __syncthreads();
        s[t] += add;
        __syncthreads();
    }
    if (i < N_NODES) rowstart[i] = bsums[blockIdx.x] + s[t] - c;   // exclusive
}

// ---------------- build CSR: col + hop-invariant coefficient a*out_norm[src] ----------------
__global__ void k_scatter(const int* __restrict__ src, const int* __restrict__ dst,
                          const float* __restrict__ eval, const float* __restrict__ denom,
                          const float* __restrict__ onorm, const int* __restrict__ rowstart,
                          int* fill, int* __restrict__ colA, float* __restrict__ valA) {
    int e = blockIdx.x * 256 + threadIdx.x;
    if (e >= N_EDGES) return;
    int s = src[e], d = dst[e];
    float a = eval[e] / denom[d];
    int pos = rowstart[d] + atomicAdd(&fill[d], 1);
    colA[pos] = s;
    valA[pos] = a * onorm[s];
}

// ---------------- SpMM hop: y[d] = innorm[d] * sum_e val[e] * x[col[e]] ----------------
// one wave per dst node, lane = feature; zero atomics; 256B coalesced gathers.
__global__ __launch_bounds__(256) void k_spmm(
        const float* __restrict__ x, const int* __restrict__ rowstart,
        const int* __restrict__ colA, const float* __restrict__ valA,
        const float* __restrict__ innorm, float* __restrict__ y) {
    int wid  = (blockIdx.x * 256 + threadIdx.x) >> 6;
    int lane = threadIdx.x & 63;
    if (wid >= N_NODES) return;
    int b = rowstart[wid], eend = rowstart[wid + 1];
    float acc0 = 0.f, acc1 = 0.f;
    for (int i = b; i < eend; i += 64) {
        int j = i + lane;
        int c = 0; float v = 0.f;
        if (j < eend) { c = colA[j]; v = valA[j]; }
        int cnt = min(64, eend - i);
        int t = 0;
        for (; t + 1 < cnt; t += 2) {     // 2 gathers in flight per iter
            int   c0 = __shfl(c, t),     c1 = __shfl(c, t + 1);
            float v0 = __shfl(v, t),     v1 = __shfl(v, t + 1);
            float g0 = x[(size_t)c0 * OUT_F + lane];
            float g1 = x[(size_t)c1 * OUT_F + lane];
            acc0 += v0 * g0;
            acc1 += v1 * g1;
        }
        if (t < cnt) {
            int c0 = __shfl(c, t); float v0 = __shfl(v, t);
            acc0 += v0 * x[(size_t)c0 * OUT_F + lane];
        }
    }
    y[(size_t)wid * OUT_F + lane] = innorm[wid] * (acc0 + acc1);
}

extern "C" void kernel_launch(void* const* d_in, const int* in_sizes, int n_in,
                              void* d_out, int out_size, void* d_ws, size_t ws_size,
                              hipStream_t stream) {
    const float* feat   = (const float*)d_in[0];
    const float* W      = (const float*)d_in[1];
    const float* attn_l = (const float*)d_in[2];
    const float* attn_r = (const float*)d_in[3];
    const int*   src    = (const int*)d_in[4];
    const int*   dst    = (const int*)d_in[5];
    float* out = (float*)d_out;

    // workspace layout (all 4-byte elems, 256B-aligned slices); total ~75 MB
    char* p = (char*)d_ws;
    auto alloc = [&](size_t elems) {
        void* r = (void*)p;
        p += ((elems * 4 + 255) / 256) * 256;
        return r;
    };
    float*    h       = (float*)   alloc((size_t)N_NODES * OUT_F);
    float*    x1      = (float*)   alloc((size_t)N_NODES * OUT_F);
    float*    el      = (float*)   alloc(N_NODES);
    float*    er      = (float*)   alloc(N_NODES);
    float*    eval    = (float*)   alloc(N_EDGES);
    unsigned* emax_u  = (unsigned*)alloc(N_NODES);
    float*    emax_f  = (float*)   alloc(N_NODES);
    float*    denom   = (float*)   alloc(N_NODES);
    int*      outdeg  = (int*)     alloc(N_NODES);
    int*      indeg   = (int*)     alloc(N_NODES);
    float*    onorm   = (float*)   alloc(N_NODES);
    float*    innorm  = (float*)   alloc(N_NODES);
    int*      rowstart= (int*)     alloc(N_NODES + 1);
    int*      fill    = (int*)     alloc(N_NODES);
    int*      bsums   = (int*)     alloc(128);
    int*      colA    = (int*)     alloc(N_EDGES);
    float*    valA    = (float*)   alloc(N_EDGES);

    const int nb_n = (N_NODES + 255) / 256;
    const int nb_e = (N_EDGES + 255) / 256;

    k_init<<<nb_n, 256, 0, stream>>>(emax_u, denom, outdeg, indeg, fill, rowstart);
    k_gemm<<<N_NODES / 16, 256, 0, stream>>>(feat, W, attn_l, attn_r, h, el, er);
    k_edge1<<<nb_e, 256, 0, stream>>>(src, dst, el, er, eval, emax_u, outdeg, indeg);
    k_node<<<nb_n, 256, 0, stream>>>(emax_u, outdeg, indeg, emax_f, onorm, innorm);
    k_edge2<<<nb_e, 256, 0, stream>>>(dst, emax_f, eval, denom);
    k_scan1<<<NBLK, SCAN_B, 0, stream>>>(indeg, bsums);
    k_scan2<<<1, 128, 0, stream>>>(bsums);
    k_scan3<<<NBLK, SCAN_B, 0, stream>>>(indeg, bsums, rowstart);
    k_scatter<<<nb_e, 256, 0, stream>>>(src, dst, eval, denom, onorm, rowstart, fill, colA, valA);

    const int nb_spmm = (N_NODES + 3) / 4;   // 4 waves/block, 1 wave/node
    k_spmm<<<nb_spmm, 256, 0, stream>>>(h,  rowstart, colA, valA, innorm, x1);
    k_spmm<<<nb_spmm, 256, 0, stream>>>(x1, rowstart, colA, valA, innorm, h);
    k_spmm<<<nb_spmm, 256, 0, stream>>>(h,  rowstart, colA, valA, innorm, out);
}

// Round 2
// 611.706 us; speedup vs baseline: 1.1813x; 1.1813x over previous
//
#include <hip/hip_runtime.h>
#include <math.h>

#define N_NODES 100000
#define N_EDGES 1600000
#define IN_F 128
#define OUT_F 64
#define NEG_SLOPE 0.2f
#define NSHARD 8

#define SCAN_B 1024
#define NBLK ((N_NODES + SCAN_B - 1) / SCAN_B)   // 98

__device__ __forceinline__ float wsum(float v) {
    #pragma unroll
    for (int off = 32; off; off >>= 1) v += __shfl_xor(v, off);
    return v;
}

// ---------------- Kernel A: h = feat @ W^T, fused el/er ----------------
__global__ __launch_bounds__(256) void k_gemm(
        const float* __restrict__ feat, const float* __restrict__ W,
        const float* __restrict__ attn_l, const float* __restrict__ attn_r,
        float* __restrict__ h, float* __restrict__ el, float* __restrict__ er) {
    __shared__ __align__(16) float wlds[OUT_F * 132];
    __shared__ __align__(16) float flds[4][4][IN_F];
    int tid = threadIdx.x;
    for (int i = tid; i < OUT_F * IN_F; i += 256)
        wlds[(i >> 7) * 132 + (i & 127)] = W[i];

    int wave = tid >> 6, lane = tid & 63;
    int wid = blockIdx.x * 4 + wave;
    int n0  = wid * 4;

    const float4* fsrc = (const float4*)(feat + (size_t)n0 * IN_F);
    float4* fdst = (float4*)(&flds[wave][0][0]);
    fdst[lane]      = fsrc[lane];
    fdst[lane + 64] = fsrc[lane + 64];
    __syncthreads();

    float acc0 = 0.f, acc1 = 0.f, acc2 = 0.f, acc3 = 0.f;
    #pragma unroll
    for (int k4 = 0; k4 < 32; ++k4) {
        float4 w  = *(const float4*)&wlds[lane * 132 + k4 * 4];
        float4 f0 = *(const float4*)&flds[wave][0][k4 * 4];
        float4 f1 = *(const float4*)&flds[wave][1][k4 * 4];
        float4 f2 = *(const float4*)&flds[wave][2][k4 * 4];
        float4 f3 = *(const float4*)&flds[wave][3][k4 * 4];
        acc0 += w.x * f0.x + w.y * f0.y + w.z * f0.z + w.w * f0.w;
        acc1 += w.x * f1.x + w.y * f1.y + w.z * f1.z + w.w * f1.w;
        acc2 += w.x * f2.x + w.y * f2.y + w.z * f2.z + w.w * f2.w;
        acc3 += w.x * f3.x + w.y * f3.y + w.z * f3.z + w.w * f3.w;
    }
    h[(size_t)(n0 + 0) * OUT_F + lane] = acc0;
    h[(size_t)(n0 + 1) * OUT_F + lane] = acc1;
    h[(size_t)(n0 + 2) * OUT_F + lane] = acc2;
    h[(size_t)(n0 + 3) * OUT_F + lane] = acc3;

    float al = attn_l[lane], ar = attn_r[lane];
    float l0 = wsum(acc0 * al), r0 = wsum(acc0 * ar);
    float l1 = wsum(acc1 * al), r1 = wsum(acc1 * ar);
    float l2 = wsum(acc2 * al), r2 = wsum(acc2 * ar);
    float l3 = wsum(acc3 * al), r3 = wsum(acc3 * ar);
    if (lane == 0) {
        el[n0 + 0] = l0; er[n0 + 0] = r0;
        el[n0 + 1] = l1; er[n0 + 1] = r1;
        el[n0 + 2] = l2; er[n0 + 2] = r2;
        el[n0 + 3] = l3; er[n0 + 3] = r3;
    }
}

// ---------------- edge pass: sharded degree histograms + exp(score) ----------------
// No atomicMax: raw softmax is numerically safe here (|score| <~ 10).
__global__ void k_edge1(const int* __restrict__ src, const int* __restrict__ dst,
                        const float* __restrict__ el, const float* __restrict__ er,
                        float* __restrict__ pexp, int* odsh, int* idsh) {
    int e = blockIdx.x * 256 + threadIdx.x;
    if (e >= N_EDGES) return;
    int s = src[e], d = dst[e];
    int sh = (threadIdx.x & (NSHARD - 1)) * N_NODES;
    atomicAdd(&odsh[sh + s], 1);
    atomicAdd(&idsh[sh + d], 1);
    float v = el[s] + er[d];
    v = (v > 0.f) ? v : NEG_SLOPE * v;
    pexp[e] = __expf(v);
}

// ---------------- per-node: reduce shards, degree norms ----------------
__global__ void k_node(const int* __restrict__ odsh, const int* __restrict__ idsh,
                       int* __restrict__ indeg, float* __restrict__ onorm,
                       float* __restrict__ innorm, int* rowstart) {
    int i = blockIdx.x * blockDim.x + threadIdx.x;
    if (i == 0) rowstart[N_NODES] = N_EDGES;
    if (i >= N_NODES) return;
    int od = 0, id = 0;
    #pragma unroll
    for (int k = 0; k < NSHARD; ++k) {
        od += odsh[k * N_NODES + i];
        id += idsh[k * N_NODES + i];
    }
    indeg[i]  = id;
    onorm[i]  = 1.0f / sqrtf((float)max(od, 1));
    innorm[i] = sqrtf((float)max(id, 1));
}

// ---------------- two-level exclusive scan of indeg -> rowstart ----------------
__global__ __launch_bounds__(SCAN_B) void k_scan1(const int* __restrict__ indeg, int* bsums) {
    __shared__ int s[SCAN_B];
    int t = threadIdx.x, i = blockIdx.x * SCAN_B + t;
    s[t] = (i < N_NODES) ? indeg[i] : 0;
    __syncthreads();
    for (int d = SCAN_B / 2; d; d >>= 1) {
        if (t < d) s[t] += s[t + d];
        __syncthreads();
    }
    if (t == 0) bsums[blockIdx.x] = s[0];
}

__global__ __launch_bounds__(128) void k_scan2(int* bsums) {
    __shared__ int s[128];
    int t = threadIdx.x;
    int v = (t < NBLK) ? bsums[t] : 0;
    s[t] = v;
    __syncthreads();
    for (int d = 1; d < 128; d <<= 1) {
        int add = (t >= d) ? s[t - d] : 0;
        __syncthreads();
        s[t] += add;
        __syncthreads();
    }
    if (t < NBLK) bsums[t] = s[t] - v;
}

__global__ __launch_bounds__(SCAN_B) void k_scan3(const int* __restrict__ indeg,
                                                  const int* __restrict__ bsums,
                                                  int* rowstart) {
    __shared__ int s[SCAN_B];
    int t = threadIdx.x, i = blockIdx.x * SCAN_B + t;
    int c = (i < N_NODES) ? indeg[i] : 0;
    s[t] = c;
    __syncthreads();
    for (int d = 1; d < SCAN_B; d <<= 1) {
        int add = (t >= d) ? s[t - d] : 0;
        __syncthreads();
        s[t] += add;
        __syncthreads();
    }
    if (i < N_NODES) rowstart[i] = bsums[blockIdx.x] + s[t] - c;
}

// ---------------- build CSR: one 8B AoS record {col, pexp} per edge ----------------
__global__ void k_scatter(const int* __restrict__ src, const int* __restrict__ dst,
                          const float* __restrict__ pexp, const int* __restrict__ rowstart,
                          int* fill, float2* __restrict__ csr) {
    int e = blockIdx.x * 256 + threadIdx.x;
    if (e >= N_EDGES) return;
    int s = src[e], d = dst[e];
    int pos = rowstart[d] + atomicAdd(&fill[d], 1);
    float2 w;
    w.x = __int_as_float(s);
    w.y = pexp[e];
    csr[pos] = w;
}

// ---------------- denom row-sums (no atomics) + per-hop scales + z0 = onorm*h ----
__global__ __launch_bounds__(256) void k_denom(
        const float2* __restrict__ csr, const int* __restrict__ rowstart,
        const float* __restrict__ onorm, const float* __restrict__ innorm,
        const float* __restrict__ h, float* __restrict__ z0,
        float* __restrict__ s12, float* __restrict__ s3) {
    int wid  = (blockIdx.x * 256 + threadIdx.x) >> 6;
    int lane = threadIdx.x & 63;
    if (wid >= N_NODES) return;
    int b = rowstart[wid], en = rowstart[wid + 1];
    float sum = 0.f;
    for (int j = b + lane; j < en; j += 64) sum += csr[j].y;
    sum = wsum(sum);
    float on = onorm[wid];
    if (lane == 0) {
        float rs = (sum > 0.f) ? innorm[wid] / sum : 0.f;
        s12[wid] = on * rs;
        s3[wid]  = rs;
    }
    z0[(size_t)wid * OUT_F + lane] = on * h[(size_t)wid * OUT_F + lane];
}

// ---------------- SpMM hop: y[d] = sigma[d] * sum_e pexp_e * x[col_e] ----------------
__global__ __launch_bounds__(256) void k_spmm(
        const float* __restrict__ x, const int* __restrict__ rowstart,
        const float2* __restrict__ csr, const float* __restrict__ sigma,
        float* __restrict__ y) {
    int wid  = (blockIdx.x * 256 + threadIdx.x) >> 6;
    int lane = threadIdx.x & 63;
    if (wid >= N_NODES) return;
    int b = rowstart[wid], eend = rowstart[wid + 1];
    float acc0 = 0.f, acc1 = 0.f;
    for (int i = b; i < eend; i += 64) {
        int j = i + lane;
        int c = 0; float v = 0.f;
        if (j < eend) { float2 w = csr[j]; c = __float_as_int(w.x); v = w.y; }
        int cnt = min(64, eend - i);
        int t = 0;
        for (; t + 1 < cnt; t += 2) {
            int   c0 = __shfl(c, t),     c1 = __shfl(c, t + 1);
            float v0 = __shfl(v, t),     v1 = __shfl(v, t + 1);
            acc0 += v0 * x[(size_t)c0 * OUT_F + lane];
            acc1 += v1 * x[(size_t)c1 * OUT_F + lane];
        }
        if (t < cnt) {
            int c0 = __shfl(c, t); float v0 = __shfl(v, t);
            acc0 += v0 * x[(size_t)c0 * OUT_F + lane];
        }
    }
    y[(size_t)wid * OUT_F + lane] = sigma[wid] * (acc0 + acc1);
}

extern "C" void kernel_launch(void* const* d_in, const int* in_sizes, int n_in,
                              void* d_out, int out_size, void* d_ws, size_t ws_size,
                              hipStream_t stream) {
    const float* feat   = (const float*)d_in[0];
    const float* W      = (const float*)d_in[1];
    const float* attn_l = (const float*)d_in[2];
    const float* attn_r = (const float*)d_in[3];
    const int*   src    = (const int*)d_in[4];
    const int*   dst    = (const int*)d_in[5];
    float* out = (float*)d_out;

    char* p = (char*)d_ws;
    auto alloc = [&](size_t elems) {
        void* r = (void*)p;
        p += ((elems * 4 + 255) / 256) * 256;
        return r;
    };
    // Union region U (25.6 MB): shard tables + fill live early; zbuf lives late.
    // Lifetimes: odsh/idsh dead after k_node; fill dead after k_scatter;
    // zbuf first written in k_denom (after k_scatter). No overlap.
    char* ubase = (char*)alloc((size_t)N_NODES * OUT_F);   // 25.6 MB
    int*   odsh = (int*)ubase;                             // NSHARD*N ints (3.2 MB)
    int*   idsh = odsh + (size_t)NSHARD * N_NODES;         // 3.2 MB
    int*   fill = idsh + (size_t)NSHARD * N_NODES;         // 0.4 MB
    float* zbuf = (float*)ubase;                           // 25.6 MB (late)

    float*  h        = (float*) alloc((size_t)N_NODES * OUT_F);  // 25.6 MB
    float*  el       = (float*) alloc(N_NODES);
    float*  er       = (float*) alloc(N_NODES);
    float*  pexp     = (float*) alloc(N_EDGES);                  // 6.4 MB
    int*    indeg    = (int*)   alloc(N_NODES);
    float*  onorm    = (float*) alloc(N_NODES);
    float*  innorm   = (float*) alloc(N_NODES);
    float*  s12      = (float*) alloc(N_NODES);
    float*  s3       = (float*) alloc(N_NODES);
    int*    rowstart = (int*)   alloc(N_NODES + 1);
    int*    bsums    = (int*)   alloc(128);
    float2* csr      = (float2*)alloc((size_t)N_EDGES * 2);      // 12.8 MB

    const int nb_n = (N_NODES + 255) / 256;
    const int nb_e = (N_EDGES + 255) / 256;

    // zero shard tables + fill in one memset (contiguous in U)
    hipMemsetAsync(ubase, 0, ((size_t)2 * NSHARD * N_NODES + N_NODES) * 4, stream);

    k_gemm<<<N_NODES / 16, 256, 0, stream>>>(feat, W, attn_l, attn_r, h, el, er);
    k_edge1<<<nb_e, 256, 0, stream>>>(src, dst, el, er, pexp, odsh, idsh);
    k_node<<<nb_n, 256, 0, stream>>>(odsh, idsh, indeg, onorm, innorm, rowstart);
    k_scan1<<<NBLK, SCAN_B, 0, stream>>>(indeg, bsums);
    k_scan2<<<1, 128, 0, stream>>>(bsums);
    k_scan3<<<NBLK, SCAN_B, 0, stream>>>(indeg, bsums, rowstart);
    k_scatter<<<nb_e, 256, 0, stream>>>(src, dst, pexp, rowstart, fill, csr);
    k_denom<<<(N_NODES + 3) / 4, 256, 0, stream>>>(csr, rowstart, onorm, innorm, h, zbuf, s12, s3);

    const int nb_spmm = (N_NODES + 3) / 4;
    k_spmm<<<nb_spmm, 256, 0, stream>>>(zbuf, rowstart, csr, s12, h);    // hop 1 -> h buffer
    k_spmm<<<nb_spmm, 256, 0, stream>>>(h,    rowstart, csr, s12, zbuf); // hop 2 -> zbuf
    k_spmm<<<nb_spmm, 256, 0, stream>>>(zbuf, rowstart, csr, s3,  out);  // hop 3 -> out
}

// Round 3
// 495.902 us; speedup vs baseline: 1.4572x; 1.2335x over previous
//
#include <hip/hip_runtime.h>
#include <math.h>

#define N_NODES 100000
#define N_EDGES 1600000
#define IN_F 128
#define OUT_F 64
#define NEG_SLOPE 0.2f

#define NBUCK 391          // ceil(N_NODES / 256): bucket = 256 consecutive node ids
#define PB 256             // phase-1/3 edge-slice blocks
#define EPB (N_EDGES / PB) // 6250 edges per slice

__device__ __forceinline__ float wsum(float v) {
    #pragma unroll
    for (int off = 32; off; off >>= 1) v += __shfl_xor(v, off);
    return v;
}

// ---------------- h = feat @ W^T, fused el/er ----------------
__global__ __launch_bounds__(256) void k_gemm(
        const float* __restrict__ feat, const float* __restrict__ W,
        const float* __restrict__ attn_l, const float* __restrict__ attn_r,
        float* __restrict__ h, float* __restrict__ el, float* __restrict__ er) {
    __shared__ __align__(16) float wlds[OUT_F * 132];
    __shared__ __align__(16) float flds[4][4][IN_F];
    int tid = threadIdx.x;
    for (int i = tid; i < OUT_F * IN_F; i += 256)
        wlds[(i >> 7) * 132 + (i & 127)] = W[i];

    int wave = tid >> 6, lane = tid & 63;
    int wid = blockIdx.x * 4 + wave;
    int n0  = wid * 4;

    const float4* fsrc = (const float4*)(feat + (size_t)n0 * IN_F);
    float4* fdst = (float4*)(&flds[wave][0][0]);
    fdst[lane]      = fsrc[lane];
    fdst[lane + 64] = fsrc[lane + 64];
    __syncthreads();

    float acc0 = 0.f, acc1 = 0.f, acc2 = 0.f, acc3 = 0.f;
    #pragma unroll
    for (int k4 = 0; k4 < 32; ++k4) {
        float4 w  = *(const float4*)&wlds[lane * 132 + k4 * 4];
        float4 f0 = *(const float4*)&flds[wave][0][k4 * 4];
        float4 f1 = *(const float4*)&flds[wave][1][k4 * 4];
        float4 f2 = *(const float4*)&flds[wave][2][k4 * 4];
        float4 f3 = *(const float4*)&flds[wave][3][k4 * 4];
        acc0 += w.x * f0.x + w.y * f0.y + w.z * f0.z + w.w * f0.w;
        acc1 += w.x * f1.x + w.y * f1.y + w.z * f1.z + w.w * f1.w;
        acc2 += w.x * f2.x + w.y * f2.y + w.z * f2.z + w.w * f2.w;
        acc3 += w.x * f3.x + w.y * f3.y + w.z * f3.z + w.w * f3.w;
    }
    h[(size_t)(n0 + 0) * OUT_F + lane] = acc0;
    h[(size_t)(n0 + 1) * OUT_F + lane] = acc1;
    h[(size_t)(n0 + 2) * OUT_F + lane] = acc2;
    h[(size_t)(n0 + 3) * OUT_F + lane] = acc3;

    float al = attn_l[lane], ar = attn_r[lane];
    float l0 = wsum(acc0 * al), r0 = wsum(acc0 * ar);
    float l1 = wsum(acc1 * al), r1 = wsum(acc1 * ar);
    float l2 = wsum(acc2 * al), r2 = wsum(acc2 * ar);
    float l3 = wsum(acc3 * al), r3 = wsum(acc3 * ar);
    if (lane == 0) {
        el[n0 + 0] = l0; er[n0 + 0] = r0;
        el[n0 + 1] = l1; er[n0 + 1] = r1;
        el[n0 + 2] = l2; er[n0 + 2] = r2;
        el[n0 + 3] = l3; er[n0 + 3] = r3;
    }
}

// ---------------- Phase 1: per-block bucket histogram (LDS) + outdeg atomics ----
// cntg layout: cntg[k*PB + b] (bucket-major -> coalesced for phases 2b/3)
__global__ __launch_bounds__(256) void k_hist(
        const int* __restrict__ src, const int* __restrict__ dst,
        int* outdeg, int* tot, int* __restrict__ cntg) {
    __shared__ int hc[NBUCK];
    int t = threadIdx.x, b = blockIdx.x;
    for (int k = t; k < NBUCK; k += 256) hc[k] = 0;
    __syncthreads();
    int base = b * EPB;
    for (int i = t; i < EPB; i += 256) {
        int e = base + i;
        atomicAdd(&hc[dst[e] >> 8], 1);
        atomicAdd(&outdeg[src[e]], 1);
    }
    __syncthreads();
    for (int k = t; k < NBUCK; k += 256) {
        int c = hc[k];
        cntg[k * PB + b] = c;
        if (c) atomicAdd(&tot[k], c);
    }
}

// ---------------- Phase 2a: exclusive scan of bucket totals -> bstart[0..NBUCK] --
__global__ __launch_bounds__(512) void k_bstart(const int* __restrict__ tot, int* bstart) {
    __shared__ int s[512];
    int t = threadIdx.x;
    int v = (t < NBUCK) ? tot[t] : 0;
    s[t] = v;
    __syncthreads();
    for (int d = 1; d < 512; d <<= 1) {
        int a = (t >= d) ? s[t - d] : 0;
        __syncthreads();
        s[t] += a;
        __syncthreads();
    }
    if (t <= NBUCK) bstart[t] = s[t] - v;   // t==NBUCK: v=0 -> total = N_EDGES
}

// ---------------- Phase 2b: per-(bucket,block) offsets, in place over cntg -------
__global__ __launch_bounds__(256) void k_blockoff(const int* __restrict__ bstart, int* cntg) {
    __shared__ int s[256];
    int k = blockIdx.x, t = threadIdx.x;
    int c = cntg[k * PB + t];
    s[t] = c;
    __syncthreads();
    for (int d = 1; d < 256; d <<= 1) {
        int a = (t >= d) ? s[t - d] : 0;
        __syncthreads();
        s[t] += a;
        __syncthreads();
    }
    cntg[k * PB + t] = bstart[k] + s[t] - c;
}

// ---------------- Phase 3: atomic-free scatter into bucket order ------------------
// record: {src(17b) | dst_low(8b)<<17, pexp}; pexp computed inline (leaky+exp)
__global__ __launch_bounds__(256) void k_scatter3(
        const int* __restrict__ src, const int* __restrict__ dst,
        const float* __restrict__ el, const float* __restrict__ er,
        const int* __restrict__ off, int2* __restrict__ tmp) {
    __shared__ int lOff[NBUCK];
    __shared__ int lFill[NBUCK];
    int t = threadIdx.x, b = blockIdx.x;
    for (int k = t; k < NBUCK; k += 256) { lOff[k] = off[k * PB + b]; lFill[k] = 0; }
    __syncthreads();
    int base = b * EPB;
    for (int i = t; i < EPB; i += 256) {
        int e = base + i;
        int sN = src[e], d = dst[e];
        float v = el[sN] + er[d];
        v = (v > 0.f) ? v : NEG_SLOPE * v;
        float pe = __expf(v);
        int k = d >> 8;
        int r = atomicAdd(&lFill[k], 1);          // LDS atomic (on-CU)
        int2 rec;
        rec.x = sN | ((d & 255) << 17);
        rec.y = __float_as_int(pe);
        tmp[lOff[k] + r] = rec;
    }
}

// ---------------- Phase 4: per-bucket fine sort -> CSR, rowstart, denom, scales ---
__global__ __launch_bounds__(256) void k_bucket(
        const int2* __restrict__ tmp, const int* __restrict__ bstart,
        const int* __restrict__ outdeg, float2* __restrict__ csr,
        int* __restrict__ rowstart, float* __restrict__ s12, float* __restrict__ s3) {
    __shared__ int   cs[256];
    __shared__ int   excl[256];
    __shared__ int   fill[256];
    __shared__ float dsum[256];
    int k = blockIdx.x, t = threadIdx.x;
    int base = bstart[k], end = bstart[k + 1];
    cs[t] = 0; fill[t] = 0; dsum[t] = 0.f;
    __syncthreads();
    for (int i = base + t; i < end; i += 256)
        atomicAdd(&cs[(tmp[i].x >> 17) & 255], 1);
    __syncthreads();
    int c = cs[t];
    for (int d = 1; d < 256; d <<= 1) {          // inclusive scan
        int a = (t >= d) ? cs[t - d] : 0;
        __syncthreads();
        cs[t] += a;
        __syncthreads();
    }
    excl[t] = cs[t] - c;
    __syncthreads();
    int idx = k * 256 + t;
    if (idx <= N_NODES) rowstart[idx] = base + excl[t];
    for (int i = base + t; i < end; i += 256) {
        int2 rec = tmp[i];
        int dlow = (rec.x >> 17) & 255;
        int r = atomicAdd(&fill[dlow], 1);
        float pe = __int_as_float(rec.y);
        float2 w;
        w.x = __int_as_float(rec.x & 131071);
        w.y = pe;
        csr[base + excl[dlow] + r] = w;
        atomicAdd(&dsum[dlow], pe);
    }
    __syncthreads();
    if (idx < N_NODES) {
        float inn = sqrtf((float)max(c, 1));
        float rs  = (c > 0) ? inn / dsum[t] : 0.f;
        float on  = rsqrtf((float)max(outdeg[idx], 1));
        s12[idx] = on * rs;
        s3[idx]  = rs;
    }
}

// ---------------- z0 = rsqrt(outdeg) * h (elementwise, float4) --------------------
__global__ __launch_bounds__(256) void k_z0(const float* __restrict__ h,
                                            const int* __restrict__ outdeg,
                                            float* __restrict__ z0) {
    int i = blockIdx.x * 256 + threadIdx.x;      // float4 index; node = i/16
    float on = rsqrtf((float)max(outdeg[i >> 4], 1));
    float4 v = ((const float4*)h)[i];
    v.x *= on; v.y *= on; v.z *= on; v.w *= on;
    ((float4*)z0)[i] = v;
}

// ---------------- SpMM hop: y[d] = sigma[d] * sum_e pexp_e * x[col_e] -------------
__global__ __launch_bounds__(256) void k_spmm(
        const float* __restrict__ x, const int* __restrict__ rowstart,
        const float2* __restrict__ csr, const float* __restrict__ sigma,
        float* __restrict__ y) {
    int wid  = (blockIdx.x * 256 + threadIdx.x) >> 6;
    int lane = threadIdx.x & 63;
    if (wid >= N_NODES) return;
    int b = rowstart[wid], eend = rowstart[wid + 1];
    float acc0 = 0.f, acc1 = 0.f;
    for (int i = b; i < eend; i += 64) {
        int j = i + lane;
        int c = 0; float v = 0.f;
        if (j < eend) { float2 w = csr[j]; c = __float_as_int(w.x); v = w.y; }
        int cnt = min(64, eend - i);
        int t = 0;
        for (; t + 1 < cnt; t += 2) {
            int   c0 = __shfl(c, t),     c1 = __shfl(c, t + 1);
            float v0 = __shfl(v, t),     v1 = __shfl(v, t + 1);
            acc0 += v0 * x[(size_t)c0 * OUT_F + lane];
            acc1 += v1 * x[(size_t)c1 * OUT_F + lane];
        }
        if (t < cnt) {
            int c0 = __shfl(c, t); float v0 = __shfl(v, t);
            acc0 += v0 * x[(size_t)c0 * OUT_F + lane];
        }
    }
    y[(size_t)wid * OUT_F + lane] = sigma[wid] * (acc0 + acc1);
}

extern "C" void kernel_launch(void* const* d_in, const int* in_sizes, int n_in,
                              void* d_out, int out_size, void* d_ws, size_t ws_size,
                              hipStream_t stream) {
    const float* feat   = (const float*)d_in[0];
    const float* W      = (const float*)d_in[1];
    const float* attn_l = (const float*)d_in[2];
    const float* attn_r = (const float*)d_in[3];
    const int*   src    = (const int*)d_in[4];
    const int*   dst    = (const int*)d_in[5];
    float* out = (float*)d_out;

    char* p = (char*)d_ws;
    auto alloc = [&](size_t elems) {
        void* r = (void*)p;
        p += ((elems * 4 + 255) / 256) * 256;
        return r;
    };
    // Union region U (25.6 MB): tmp (12.8 MB) dead after k_bucket; zbuf born at k_z0.
    char* ubase = (char*)alloc((size_t)N_NODES * OUT_F);
    int2*  tmp  = (int2*)ubase;
    float* zbuf = (float*)ubase;

    float*  h        = (float*) alloc((size_t)N_NODES * OUT_F);   // 25.6 MB
    float*  el       = (float*) alloc(N_NODES);
    float*  er       = (float*) alloc(N_NODES);
    float2* csr      = (float2*)alloc((size_t)N_EDGES * 2);       // 12.8 MB
    int*    meta     = (int*)   alloc(N_NODES + NBUCK);           // outdeg + tot
    int*    outdeg   = meta;
    int*    tot      = meta + N_NODES;
    int*    bstart   = (int*)   alloc(NBUCK + 1);
    int*    cntg     = (int*)   alloc((size_t)NBUCK * PB);        // counts -> offsets
    int*    rowstart = (int*)   alloc(N_NODES + 1);
    float*  s12      = (float*) alloc(N_NODES);
    float*  s3       = (float*) alloc(N_NODES);

    hipMemsetAsync(meta, 0, (size_t)(N_NODES + NBUCK) * 4, stream);

    k_gemm    <<<N_NODES / 16, 256, 0, stream>>>(feat, W, attn_l, attn_r, h, el, er);
    k_hist    <<<PB,    256, 0, stream>>>(src, dst, outdeg, tot, cntg);
    k_bstart  <<<1,     512, 0, stream>>>(tot, bstart);
    k_blockoff<<<NBUCK, 256, 0, stream>>>(bstart, cntg);
    k_scatter3<<<PB,    256, 0, stream>>>(src, dst, el, er, cntg, tmp);
    k_bucket  <<<NBUCK, 256, 0, stream>>>(tmp, bstart, outdeg, csr, rowstart, s12, s3);
    k_z0      <<<(N_NODES * OUT_F / 4) / 256, 256, 0, stream>>>(h, outdeg, zbuf);

    const int nb_spmm = (N_NODES + 3) / 4;
    k_spmm<<<nb_spmm, 256, 0, stream>>>(zbuf, rowstart, csr, s12, h);    // hop 1
    k_spmm<<<nb_spmm, 256, 0, stream>>>(h,    rowstart, csr, s12, zbuf); // hop 2
    k_spmm<<<nb_spmm, 256, 0, stream>>>(zbuf, rowstart, csr, s3,  out);  // hop 3
}

// Round 4
// 426.870 us; speedup vs baseline: 1.6928x; 1.1617x over previous
//
#include <hip/hip_runtime.h>
#include <math.h>

#define N_NODES 100000
#define N_EDGES 1600000
#define IN_F 128
#define OUT_F 64
#define NEG_SLOPE 0.2f

#define NBUCK 391          // ceil(N_NODES / 256): bucket = 256 consecutive node ids
#define PB 512             // edge-slice blocks for hist/scatter
#define EPB (N_EDGES / PB) // 3125 edges per slice

__device__ __forceinline__ float wsum(float v) {
    #pragma unroll
    for (int off = 32; off; off >>= 1) v += __shfl_xor(v, off);
    return v;
}

// ---------------- h = feat @ W^T, fused el/er ----------------
__global__ __launch_bounds__(256) void k_gemm(
        const float* __restrict__ feat, const float* __restrict__ W,
        const float* __restrict__ attn_l, const float* __restrict__ attn_r,
        float* __restrict__ h, float* __restrict__ el, float* __restrict__ er) {
    __shared__ __align__(16) float wlds[OUT_F * 132];
    __shared__ __align__(16) float flds[4][4][IN_F];
    int tid = threadIdx.x;
    for (int i = tid; i < OUT_F * IN_F; i += 256)
        wlds[(i >> 7) * 132 + (i & 127)] = W[i];

    int wave = tid >> 6, lane = tid & 63;
    int wid = blockIdx.x * 4 + wave;
    int n0  = wid * 4;

    const float4* fsrc = (const float4*)(feat + (size_t)n0 * IN_F);
    float4* fdst = (float4*)(&flds[wave][0][0]);
    fdst[lane]      = fsrc[lane];
    fdst[lane + 64] = fsrc[lane + 64];
    __syncthreads();

    float acc0 = 0.f, acc1 = 0.f, acc2 = 0.f, acc3 = 0.f;
    #pragma unroll
    for (int k4 = 0; k4 < 32; ++k4) {
        float4 w  = *(const float4*)&wlds[lane * 132 + k4 * 4];
        float4 f0 = *(const float4*)&flds[wave][0][k4 * 4];
        float4 f1 = *(const float4*)&flds[wave][1][k4 * 4];
        float4 f2 = *(const float4*)&flds[wave][2][k4 * 4];
        float4 f3 = *(const float4*)&flds[wave][3][k4 * 4];
        acc0 += w.x * f0.x + w.y * f0.y + w.z * f0.z + w.w * f0.w;
        acc1 += w.x * f1.x + w.y * f1.y + w.z * f1.z + w.w * f1.w;
        acc2 += w.x * f2.x + w.y * f2.y + w.z * f2.z + w.w * f2.w;
        acc3 += w.x * f3.x + w.y * f3.y + w.z * f3.z + w.w * f3.w;
    }
    h[(size_t)(n0 + 0) * OUT_F + lane] = acc0;
    h[(size_t)(n0 + 1) * OUT_F + lane] = acc1;
    h[(size_t)(n0 + 2) * OUT_F + lane] = acc2;
    h[(size_t)(n0 + 3) * OUT_F + lane] = acc3;

    float al = attn_l[lane], ar = attn_r[lane];
    float l0 = wsum(acc0 * al), r0 = wsum(acc0 * ar);
    float l1 = wsum(acc1 * al), r1 = wsum(acc1 * ar);
    float l2 = wsum(acc2 * al), r2 = wsum(acc2 * ar);
    float l3 = wsum(acc3 * al), r3 = wsum(acc3 * ar);
    if (lane == 0) {
        el[n0 + 0] = l0; er[n0 + 0] = r0;
        el[n0 + 1] = l1; er[n0 + 1] = r1;
        el[n0 + 2] = l2; er[n0 + 2] = r2;
        el[n0 + 3] = l3; er[n0 + 3] = r3;
    }
}

// ---------------- Phase 1: per-block bucket histograms (dst AND src), no atomics --
__global__ __launch_bounds__(256) void k_hist(
        const int* __restrict__ src, const int* __restrict__ dst,
        int* __restrict__ cntd, int* __restrict__ cnts) {
    __shared__ int hd[NBUCK], hs[NBUCK];
    int t = threadIdx.x, b = blockIdx.x;
    for (int k = t; k < NBUCK; k += 256) { hd[k] = 0; hs[k] = 0; }
    __syncthreads();
    int base = b * EPB;
    for (int i = t; i < EPB; i += 256) {
        atomicAdd(&hd[dst[base + i] >> 8], 1);   // LDS atomics (on-CU)
        atomicAdd(&hs[src[base + i] >> 8], 1);
    }
    __syncthreads();
    for (int k = t; k < NBUCK; k += 256) {
        cntd[k * PB + b] = hd[k];
        cnts[k * PB + b] = hs[k];
    }
}

// ---------------- bucket totals = column sums of count matrices (no atomics) ------
__global__ __launch_bounds__(256) void k_colsum(const int* __restrict__ cntd,
                                                const int* __restrict__ cnts,
                                                int* __restrict__ totd,
                                                int* __restrict__ tots) {
    __shared__ int s[256];
    int b = blockIdx.x, t = threadIdx.x;
    const int* m; int* o; int k;
    if (b < NBUCK) { m = cntd; o = totd; k = b; }
    else           { m = cnts; o = tots; k = b - NBUCK; }
    s[t] = m[k * PB + t] + m[k * PB + t + 256];
    __syncthreads();
    for (int d = 128; d; d >>= 1) { if (t < d) s[t] += s[t + d]; __syncthreads(); }
    if (t == 0) o[k] = s[0];
}

// ---------------- exclusive scans of bucket totals (both keys, one block) ---------
__global__ __launch_bounds__(512) void k_bstart(const int* __restrict__ totd,
                                                const int* __restrict__ tots,
                                                int* bstartd, int* bstarts) {
    __shared__ int s[512];
    int t = threadIdx.x;
    int v = (t < NBUCK) ? totd[t] : 0;
    s[t] = v; __syncthreads();
    for (int d = 1; d < 512; d <<= 1) { int a = (t >= d) ? s[t - d] : 0; __syncthreads(); s[t] += a; __syncthreads(); }
    if (t <= NBUCK) bstartd[t] = s[t] - v;
    __syncthreads();
    int v2 = (t < NBUCK) ? tots[t] : 0;
    s[t] = v2; __syncthreads();
    for (int d = 1; d < 512; d <<= 1) { int a = (t >= d) ? s[t - d] : 0; __syncthreads(); s[t] += a; __syncthreads(); }
    if (t <= NBUCK) bstarts[t] = s[t] - v2;
}

// ---------------- per-(bucket,block) offsets, in place, both matrices -------------
__global__ __launch_bounds__(512) void k_blockoff(const int* __restrict__ bstartd,
                                                  const int* __restrict__ bstarts,
                                                  int* cntd, int* cnts) {
    __shared__ int s[512];
    int b = blockIdx.x, t = threadIdx.x;
    int* m; const int* bs; int k;
    if (b < NBUCK) { m = cntd; bs = bstartd; k = b; }
    else           { m = cnts; bs = bstarts; k = b - NBUCK; }
    int c = m[k * PB + t];
    s[t] = c; __syncthreads();
    for (int d = 1; d < 512; d <<= 1) { int a = (t >= d) ? s[t - d] : 0; __syncthreads(); s[t] += a; __syncthreads(); }
    m[k * PB + t] = bs[k] + s[t] - c;
}

// ---------------- Phase 3: atomic-free scatter (dst records + src bytes) ----------
__global__ __launch_bounds__(256) void k_scatter3(
        const int* __restrict__ src, const int* __restrict__ dst,
        const float* __restrict__ el, const float* __restrict__ er,
        const int* __restrict__ offd, const int* __restrict__ offs,
        int2* __restrict__ tmpd, unsigned char* __restrict__ tmps) {
    __shared__ int lOffD[NBUCK], lFillD[NBUCK], lOffS[NBUCK], lFillS[NBUCK];
    int t = threadIdx.x, b = blockIdx.x;
    for (int k = t; k < NBUCK; k += 256) {
        lOffD[k] = offd[k * PB + b]; lFillD[k] = 0;
        lOffS[k] = offs[k * PB + b]; lFillS[k] = 0;
    }
    __syncthreads();
    int base = b * EPB;
    for (int i = t; i < EPB; i += 256) {
        int e = base + i;
        int sN = src[e], d = dst[e];
        float v = el[sN] + er[d];
        v = (v > 0.f) ? v : NEG_SLOPE * v;
        float pe = __expf(v);
        int kd = d >> 8;
        int rd = atomicAdd(&lFillD[kd], 1);          // LDS atomic
        int2 rec; rec.x = sN | ((d & 255) << 17); rec.y = __float_as_int(pe);
        tmpd[lOffD[kd] + rd] = rec;
        int ks = sN >> 8;
        int rs = atomicAdd(&lFillS[ks], 1);
        tmps[lOffS[ks] + rs] = (unsigned char)(sN & 255);
    }
}

// ---------------- src-bucket count -> onorm, plain stores -------------------------
__global__ __launch_bounds__(256) void k_srccnt(
        const unsigned char* __restrict__ tmps, const int* __restrict__ bstarts,
        float* __restrict__ onorm) {
    __shared__ int cnt[256];
    int k = blockIdx.x, t = threadIdx.x;
    cnt[t] = 0; __syncthreads();
    int base = bstarts[k], end = bstarts[k + 1];
    for (int i = base + t; i < end; i += 256)
        atomicAdd(&cnt[tmps[i]], 1);
    __syncthreads();
    int idx = k * 256 + t;
    if (idx < N_NODES) onorm[idx] = rsqrtf((float)max(cnt[t], 1));
}

// ---------------- Phase 4: per-bucket fine sort -> CSR, rowstart, denom, scales ---
__global__ __launch_bounds__(256) void k_bucket(
        const int2* __restrict__ tmp, const int* __restrict__ bstart,
        const float* __restrict__ onorm, float2* __restrict__ csr,
        int* __restrict__ rowstart, float* __restrict__ s12, float* __restrict__ s3) {
    __shared__ int   cs[256];
    __shared__ int   excl[256];
    __shared__ int   fill[256];
    __shared__ float dsum[256];
    int k = blockIdx.x, t = threadIdx.x;
    int base = bstart[k], end = bstart[k + 1];
    cs[t] = 0; fill[t] = 0; dsum[t] = 0.f;
    __syncthreads();
    for (int i = base + t; i < end; i += 256)
        atomicAdd(&cs[(tmp[i].x >> 17) & 255], 1);
    __syncthreads();
    int c = cs[t];
    for (int d = 1; d < 256; d <<= 1) {
        int a = (t >= d) ? cs[t - d] : 0;
        __syncthreads();
        cs[t] += a;
        __syncthreads();
    }
    excl[t] = cs[t] - c;
    __syncthreads();
    int idx = k * 256 + t;
    if (idx <= N_NODES) rowstart[idx] = base + excl[t];
    for (int i = base + t; i < end; i += 256) {
        int2 rec = tmp[i];
        int dlow = (rec.x >> 17) & 255;
        int r = atomicAdd(&fill[dlow], 1);
        float pe = __int_as_float(rec.y);
        float2 w;
        w.x = __int_as_float(rec.x & 131071);
        w.y = pe;
        csr[base + excl[dlow] + r] = w;
        atomicAdd(&dsum[dlow], pe);
    }
    __syncthreads();
    if (idx < N_NODES) {
        float inn = sqrtf((float)max(c, 1));
        float rs  = (c > 0) ? inn / dsum[t] : 0.f;
        s12[idx] = onorm[idx] * rs;
        s3[idx]  = rs;
    }
}

// ---------------- z0 = onorm * h (elementwise, float4) ----------------------------
__global__ __launch_bounds__(256) void k_z0(const float* __restrict__ h,
                                            const float* __restrict__ onorm,
                                            float* __restrict__ z0) {
    int i = blockIdx.x * 256 + threadIdx.x;      // float4 index; node = i/16
    float on = onorm[i >> 4];
    float4 v = ((const float4*)h)[i];
    v.x *= on; v.y *= on; v.z *= on; v.w *= on;
    ((float4*)z0)[i] = v;
}

// ---------------- SpMM hop: y[d] = sigma[d] * sum_e pexp_e * x[col_e] -------------
// lane = (group g = lane>>4) x (feat-quad fl = lane&15); each group gathers one
// edge's row as float4 (dwordx4); 8 edges in flight per iter; xor-reduce groups.
__global__ __launch_bounds__(256) void k_spmm(
        const float* __restrict__ x, const int* __restrict__ rowstart,
        const float2* __restrict__ csr, const float* __restrict__ sigma,
        float* __restrict__ y) {
    int wid  = (blockIdx.x * 256 + threadIdx.x) >> 6;
    int lane = threadIdx.x & 63;
    if (wid >= N_NODES) return;
    int b = rowstart[wid], eend = rowstart[wid + 1];
    int g  = lane >> 4;          // edge group 0..3
    int fl = lane & 15;          // feature quad 0..15
    float4 acc0 = {0.f, 0.f, 0.f, 0.f};
    float4 acc1 = {0.f, 0.f, 0.f, 0.f};
    for (int i = b; i < eend; i += 64) {
        int j = i + lane;
        int c = 0; float v = 0.f;
        if (j < eend) { float2 w = csr[j]; c = __float_as_int(w.x); v = w.y; }
        int cnt = min(64, eend - i);
        for (int t = 0; t < cnt; t += 8) {
            int   c0 = __shfl(c, t + g),     c1 = __shfl(c, t + 4 + g);
            float v0 = __shfl(v, t + g),     v1 = __shfl(v, t + 4 + g);
            float4 x0 = *(const float4*)&x[(size_t)c0 * OUT_F + fl * 4];
            float4 x1 = *(const float4*)&x[(size_t)c1 * OUT_F + fl * 4];
            acc0.x += v0 * x0.x; acc0.y += v0 * x0.y; acc0.z += v0 * x0.z; acc0.w += v0 * x0.w;
            acc1.x += v1 * x1.x; acc1.y += v1 * x1.y; acc1.z += v1 * x1.z; acc1.w += v1 * x1.w;
        }
    }
    float4 a;
    a.x = acc0.x + acc1.x; a.y = acc0.y + acc1.y;
    a.z = acc0.z + acc1.z; a.w = acc0.w + acc1.w;
    #pragma unroll
    for (int off = 16; off <= 32; off <<= 1) {
        a.x += __shfl_xor(a.x, off);
        a.y += __shfl_xor(a.y, off);
        a.z += __shfl_xor(a.z, off);
        a.w += __shfl_xor(a.w, off);
    }
    if (lane < 16) {
        float sg = sigma[wid];
        a.x *= sg; a.y *= sg; a.z *= sg; a.w *= sg;
        ((float4*)&y[(size_t)wid * OUT_F])[lane] = a;
    }
}

extern "C" void kernel_launch(void* const* d_in, const int* in_sizes, int n_in,
                              void* d_out, int out_size, void* d_ws, size_t ws_size,
                              hipStream_t stream) {
    const float* feat   = (const float*)d_in[0];
    const float* W      = (const float*)d_in[1];
    const float* attn_l = (const float*)d_in[2];
    const float* attn_r = (const float*)d_in[3];
    const int*   src    = (const int*)d_in[4];
    const int*   dst    = (const int*)d_in[5];
    float* out = (float*)d_out;

    char* p = (char*)d_ws;
    auto alloc = [&](size_t elems) {
        void* r = (void*)p;
        p += ((elems * 4 + 255) / 256) * 256;
        return r;
    };
    // Union region U (25.6 MB): tmpd (12.8) + tmps (1.6) early; zbuf late (k_z0+).
    char* ubase = (char*)alloc((size_t)N_NODES * OUT_F);
    int2*  tmpd = (int2*)ubase;
    unsigned char* tmps = (unsigned char*)(ubase + (size_t)N_EDGES * 8);
    float* zbuf = (float*)ubase;

    float*  h        = (float*) alloc((size_t)N_NODES * OUT_F);   // 25.6 MB
    float*  el       = (float*) alloc(N_NODES);
    float*  er       = (float*) alloc(N_NODES);
    float2* csr      = (float2*)alloc((size_t)N_EDGES * 2);       // 12.8 MB
    int*    cntd     = (int*)   alloc((size_t)NBUCK * PB);        // 0.8 MB
    int*    cnts     = (int*)   alloc((size_t)NBUCK * PB);        // 0.8 MB
    int*    totd     = (int*)   alloc(NBUCK);
    int*    tots     = (int*)   alloc(NBUCK);
    int*    bstartd  = (int*)   alloc(NBUCK + 1);
    int*    bstarts  = (int*)   alloc(NBUCK + 1);
    int*    rowstart = (int*)   alloc(N_NODES + 1);
    float*  onorm    = (float*) alloc(N_NODES);
    float*  s12      = (float*) alloc(N_NODES);
    float*  s3       = (float*) alloc(N_NODES);

    k_gemm    <<<N_NODES / 16, 256, 0, stream>>>(feat, W, attn_l, attn_r, h, el, er);
    k_hist    <<<PB,        256, 0, stream>>>(src, dst, cntd, cnts);
    k_colsum  <<<2 * NBUCK, 256, 0, stream>>>(cntd, cnts, totd, tots);
    k_bstart  <<<1,         512, 0, stream>>>(totd, tots, bstartd, bstarts);
    k_blockoff<<<2 * NBUCK, 512, 0, stream>>>(bstartd, bstarts, cntd, cnts);
    k_scatter3<<<PB,        256, 0, stream>>>(src, dst, el, er, cntd, cnts, tmpd, tmps);
    k_srccnt  <<<NBUCK,     256, 0, stream>>>(tmps, bstarts, onorm);
    k_bucket  <<<NBUCK,     256, 0, stream>>>(tmpd, bstartd, onorm, csr, rowstart, s12, s3);
    k_z0      <<<(N_NODES * OUT_F / 4) / 256, 256, 0, stream>>>(h, onorm, zbuf);

    const int nb_spmm = (N_NODES + 3) / 4;
    k_spmm<<<nb_spmm, 256, 0, stream>>>(zbuf, rowstart, csr, s12, h);    // hop 1
    k_spmm<<<nb_spmm, 256, 0, stream>>>(h,    rowstart, csr, s12, zbuf); // hop 2
    k_spmm<<<nb_spmm, 256, 0, stream>>>(zbuf, rowstart, csr, s3,  out);  // hop 3
}

// Round 5
// 404.663 us; speedup vs baseline: 1.7857x; 1.0549x over previous
//
#include <hip/hip_runtime.h>
#include <math.h>

#define N_NODES 100000
#define N_EDGES 1600000
#define IN_F 128
#define OUT_F 64
#define NEG_SLOPE 0.2f

#define NBUCK 391          // ceil(N_NODES / 256): bucket = 256 consecutive node ids
#define PB 512             // edge-slice blocks for hist/scatter
#define EPB (N_EDGES / PB) // 3125 edges per slice

// GEMM tile params
#define GM 256             // nodes per block
#define KC 32              // k-chunk
#define FSTR 260           // fT row stride (words): 16B-aligned frags, 2-way banks
#define WSTR 68            // wT row stride

__device__ __forceinline__ float wsum(float v) {
    #pragma unroll
    for (int off = 32; off; off >>= 1) v += __shfl_xor(v, off);
    return v;
}

// ---------------- GEMM: z0 = onorm * (feat @ W^T), fused el/er -------------------
// 256 threads: nid = t>>3 (8 nodes each), fid = t&7 (8 feats each). 8x8 register
// tile -> 4 b128 LDS reads per 64 FMA (0.5 B/FLOP = LDS/VALU balance point).
__global__ __launch_bounds__(256) void k_gemm(
        const float* __restrict__ feat, const float* __restrict__ W,
        const float* __restrict__ attn_l, const float* __restrict__ attn_r,
        const float* __restrict__ onorm, float* __restrict__ z0,
        float* __restrict__ el, float* __restrict__ er) {
    __shared__ __align__(16) float fT[KC * FSTR];     // 33.3 KB (k-major, transposed)
    __shared__ __align__(16) float wT[IN_F * WSTR];   // 34.8 KB (k-major)
    __shared__ float elds[GM], erds[GM];
    int t = threadIdx.x;
    int n0 = blockIdx.x * GM;

    for (int i = t; i < OUT_F * IN_F; i += 256) {     // W[64][128] -> wT[k][f]
        int f = i >> 7, k = i & 127;
        wT[k * WSTR + f] = W[i];
    }
    elds[t] = 0.f; erds[t] = 0.f;

    int nid = t >> 3, fid = t & 7;
    float acc[8][8];
    #pragma unroll
    for (int n = 0; n < 8; ++n)
        #pragma unroll
        for (int f = 0; f < 8; ++f) acc[n][f] = 0.f;

    for (int c = 0; c < IN_F / KC; ++c) {
        __syncthreads();   // fT reuse barrier (1st iter: covers wT/elds writes)
        #pragma unroll
        for (int j = 0; j < 8; ++j) {                 // stage 256 nodes x 32 k
            int q = t + j * 256;
            int node = q >> 3, kq = q & 7;
            int g = n0 + node;
            float4 v = {0.f, 0.f, 0.f, 0.f};
            if (g < N_NODES)
                v = *(const float4*)&feat[(size_t)g * IN_F + c * KC + kq * 4];
            int kl = kq * 4;
            fT[(kl + 0) * FSTR + node] = v.x;
            fT[(kl + 1) * FSTR + node] = v.y;
            fT[(kl + 2) * FSTR + node] = v.z;
            fT[(kl + 3) * FSTR + node] = v.w;
        }
        __syncthreads();
        #pragma unroll 2
        for (int kk = 0; kk < KC; ++kk) {
            const float4* wp = (const float4*)&wT[(c * KC + kk) * WSTR + fid * 8];
            float4 w0 = wp[0], w1 = wp[1];
            const float4* fp = (const float4*)&fT[kk * FSTR + nid * 8];
            float4 f0 = fp[0], f1 = fp[1];
            float fv[8] = {f0.x, f0.y, f0.z, f0.w, f1.x, f1.y, f1.z, f1.w};
            float wv[8] = {w0.x, w0.y, w0.z, w0.w, w1.x, w1.y, w1.z, w1.w};
            #pragma unroll
            for (int n = 0; n < 8; ++n)
                #pragma unroll
                for (int f = 0; f < 8; ++f)
                    acc[n][f] += fv[n] * wv[f];
        }
    }

    float al[8], ar[8];
    #pragma unroll
    for (int f = 0; f < 8; ++f) { al[f] = attn_l[fid * 8 + f]; ar[f] = attn_r[fid * 8 + f]; }
    #pragma unroll
    for (int n = 0; n < 8; ++n) {
        float pl = 0.f, pr = 0.f;
        #pragma unroll
        for (int f = 0; f < 8; ++f) { pl += acc[n][f] * al[f]; pr += acc[n][f] * ar[f]; }
        atomicAdd(&elds[nid * 8 + n], pl);
        atomicAdd(&erds[nid * 8 + n], pr);
    }
    __syncthreads();
    int g = n0 + t;
    if (g < N_NODES) { el[g] = elds[t]; er[g] = erds[t]; }

    #pragma unroll
    for (int n = 0; n < 8; ++n) {
        int gg = n0 + nid * 8 + n;
        if (gg < N_NODES) {
            float on = onorm[gg];
            float4 o0 = {acc[n][0] * on, acc[n][1] * on, acc[n][2] * on, acc[n][3] * on};
            float4 o1 = {acc[n][4] * on, acc[n][5] * on, acc[n][6] * on, acc[n][7] * on};
            float4* yp = (float4*)&z0[(size_t)gg * OUT_F + fid * 8];
            yp[0] = o0; yp[1] = o1;
        }
    }
}

// ---------------- per-block bucket histograms (dst AND src), no global atomics ----
__global__ __launch_bounds__(256) void k_hist(
        const int* __restrict__ src, const int* __restrict__ dst,
        int* __restrict__ cntd, int* __restrict__ cnts) {
    __shared__ int hd[NBUCK], hs[NBUCK];
    int t = threadIdx.x, b = blockIdx.x;
    for (int k = t; k < NBUCK; k += 256) { hd[k] = 0; hs[k] = 0; }
    __syncthreads();
    int base = b * EPB;
    for (int i = t; i < EPB; i += 256) {
        atomicAdd(&hd[dst[base + i] >> 8], 1);   // LDS atomics (on-CU)
        atomicAdd(&hs[src[base + i] >> 8], 1);
    }
    __syncthreads();
    for (int k = t; k < NBUCK; k += 256) {
        cntd[k * PB + b] = hd[k];
        cnts[k * PB + b] = hs[k];
    }
}

// ---------------- bucket totals = column sums of count matrices -------------------
__global__ __launch_bounds__(256) void k_colsum(const int* __restrict__ cntd,
                                                const int* __restrict__ cnts,
                                                int* __restrict__ totd,
                                                int* __restrict__ tots) {
    __shared__ int s[256];
    int b = blockIdx.x, t = threadIdx.x;
    const int* m; int* o; int k;
    if (b < NBUCK) { m = cntd; o = totd; k = b; }
    else           { m = cnts; o = tots; k = b - NBUCK; }
    s[t] = m[k * PB + t] + m[k * PB + t + 256];
    __syncthreads();
    for (int d = 128; d; d >>= 1) { if (t < d) s[t] += s[t + d]; __syncthreads(); }
    if (t == 0) o[k] = s[0];
}

// ---------------- exclusive scans of bucket totals (both keys) --------------------
__global__ __launch_bounds__(512) void k_bstart(const int* __restrict__ totd,
                                                const int* __restrict__ tots,
                                                int* bstartd, int* bstarts) {
    __shared__ int s[512];
    int t = threadIdx.x;
    int v = (t < NBUCK) ? totd[t] : 0;
    s[t] = v; __syncthreads();
    for (int d = 1; d < 512; d <<= 1) { int a = (t >= d) ? s[t - d] : 0; __syncthreads(); s[t] += a; __syncthreads(); }
    if (t <= NBUCK) bstartd[t] = s[t] - v;
    __syncthreads();
    int v2 = (t < NBUCK) ? tots[t] : 0;
    s[t] = v2; __syncthreads();
    for (int d = 1; d < 512; d <<= 1) { int a = (t >= d) ? s[t - d] : 0; __syncthreads(); s[t] += a; __syncthreads(); }
    if (t <= NBUCK) bstarts[t] = s[t] - v2;
}

// ---------------- per-(bucket,block) offsets, in place, both matrices -------------
__global__ __launch_bounds__(512) void k_blockoff(const int* __restrict__ bstartd,
                                                  const int* __restrict__ bstarts,
                                                  int* cntd, int* cnts) {
    __shared__ int s[512];
    int b = blockIdx.x, t = threadIdx.x;
    int* m; const int* bs; int k;
    if (b < NBUCK) { m = cntd; bs = bstartd; k = b; }
    else           { m = cnts; bs = bstarts; k = b - NBUCK; }
    int c = m[k * PB + t];
    s[t] = c; __syncthreads();
    for (int d = 1; d < 512; d <<= 1) { int a = (t >= d) ? s[t - d] : 0; __syncthreads(); s[t] += a; __syncthreads(); }
    m[k * PB + t] = bs[k] + s[t] - c;
}

// ---------------- src-key scatter (bytes only; independent of el/er) --------------
__global__ __launch_bounds__(256) void k_scatter_src(
        const int* __restrict__ src, const int* __restrict__ offs,
        unsigned char* __restrict__ tmps) {
    __shared__ int lOffS[NBUCK], lFillS[NBUCK];
    int t = threadIdx.x, b = blockIdx.x;
    for (int k = t; k < NBUCK; k += 256) { lOffS[k] = offs[k * PB + b]; lFillS[k] = 0; }
    __syncthreads();
    int base = b * EPB;
    for (int i = t; i < EPB; i += 256) {
        int sN = src[base + i];
        int ks = sN >> 8;
        int rs = atomicAdd(&lFillS[ks], 1);       // LDS atomic
        tmps[lOffS[ks] + rs] = (unsigned char)(sN & 255);
    }
}

// ---------------- src-bucket count -> onorm, plain stores -------------------------
__global__ __launch_bounds__(256) void k_srccnt(
        const unsigned char* __restrict__ tmps, const int* __restrict__ bstarts,
        float* __restrict__ onorm) {
    __shared__ int cnt[256];
    int k = blockIdx.x, t = threadIdx.x;
    cnt[t] = 0; __syncthreads();
    int base = bstarts[k], end = bstarts[k + 1];
    for (int i = base + t; i < end; i += 256)
        atomicAdd(&cnt[tmps[i]], 1);
    __syncthreads();
    int idx = k * 256 + t;
    if (idx < N_NODES) onorm[idx] = rsqrtf((float)max(cnt[t], 1));
}

// ---------------- dst-key scatter: {src|dst_low, pexp} records --------------------
__global__ __launch_bounds__(256) void k_scatter3(
        const int* __restrict__ src, const int* __restrict__ dst,
        const float* __restrict__ el, const float* __restrict__ er,
        const int* __restrict__ offd, int2* __restrict__ tmpd) {
    __shared__ int lOffD[NBUCK], lFillD[NBUCK];
    int t = threadIdx.x, b = blockIdx.x;
    for (int k = t; k < NBUCK; k += 256) { lOffD[k] = offd[k * PB + b]; lFillD[k] = 0; }
    __syncthreads();
    int base = b * EPB;
    for (int i = t; i < EPB; i += 256) {
        int e = base + i;
        int sN = src[e], d = dst[e];
        float v = el[sN] + er[d];
        v = (v > 0.f) ? v : NEG_SLOPE * v;
        float pe = __expf(v);
        int kd = d >> 8;
        int rd = atomicAdd(&lFillD[kd], 1);       // LDS atomic
        int2 rec; rec.x = sN | ((d & 255) << 17); rec.y = __float_as_int(pe);
        tmpd[lOffD[kd] + rd] = rec;
    }
}

// ---------------- per-bucket fine sort -> CSR, rowstart, denom, scales ------------
__global__ __launch_bounds__(256) void k_bucket(
        const int2* __restrict__ tmp, const int* __restrict__ bstart,
        const float* __restrict__ onorm, float2* __restrict__ csr,
        int* __restrict__ rowstart, float* __restrict__ s12, float* __restrict__ s3) {
    __shared__ int   cs[256];
    __shared__ int   excl[256];
    __shared__ int   fill[256];
    __shared__ float dsum[256];
    int k = blockIdx.x, t = threadIdx.x;
    int base = bstart[k], end = bstart[k + 1];
    cs[t] = 0; fill[t] = 0; dsum[t] = 0.f;
    __syncthreads();
    for (int i = base + t; i < end; i += 256)
        atomicAdd(&cs[(tmp[i].x >> 17) & 255], 1);
    __syncthreads();
    int c = cs[t];
    for (int d = 1; d < 256; d <<= 1) {
        int a = (t >= d) ? cs[t - d] : 0;
        __syncthreads();
        cs[t] += a;
        __syncthreads();
    }
    excl[t] = cs[t] - c;
    __syncthreads();
    int idx = k * 256 + t;
    if (idx <= N_NODES) rowstart[idx] = base + excl[t];
    for (int i = base + t; i < end; i += 256) {
        int2 rec = tmp[i];
        int dlow = (rec.x >> 17) & 255;
        int r = atomicAdd(&fill[dlow], 1);
        float pe = __int_as_float(rec.y);
        float2 w;
        w.x = __int_as_float(rec.x & 131071);
        w.y = pe;
        csr[base + excl[dlow] + r] = w;
        atomicAdd(&dsum[dlow], pe);
    }
    __syncthreads();
    if (idx < N_NODES) {
        float inn = sqrtf((float)max(c, 1));
        float rs  = (c > 0) ? inn / dsum[t] : 0.f;
        s12[idx] = onorm[idx] * rs;
        s3[idx]  = rs;
    }
}

// ---------------- SpMM hop: y[d] = sigma[d] * sum_e pexp_e * x[col_e] -------------
__global__ __launch_bounds__(256) void k_spmm(
        const float* __restrict__ x, const int* __restrict__ rowstart,
        const float2* __restrict__ csr, const float* __restrict__ sigma,
        float* __restrict__ y) {
    int wid  = (blockIdx.x * 256 + threadIdx.x) >> 6;
    int lane = threadIdx.x & 63;
    if (wid >= N_NODES) return;
    int b = rowstart[wid], eend = rowstart[wid + 1];
    int g  = lane >> 4;          // edge group 0..3
    int fl = lane & 15;          // feature quad 0..15
    float4 acc0 = {0.f, 0.f, 0.f, 0.f};
    float4 acc1 = {0.f, 0.f, 0.f, 0.f};
    for (int i = b; i < eend; i += 64) {
        int j = i + lane;
        int c = 0; float v = 0.f;
        if (j < eend) { float2 w = csr[j]; c = __float_as_int(w.x); v = w.y; }
        int cnt = min(64, eend - i);
        for (int t = 0; t < cnt; t += 8) {
            int   c0 = __shfl(c, t + g),     c1 = __shfl(c, t + 4 + g);
            float v0 = __shfl(v, t + g),     v1 = __shfl(v, t + 4 + g);
            float4 x0 = *(const float4*)&x[(size_t)c0 * OUT_F + fl * 4];
            float4 x1 = *(const float4*)&x[(size_t)c1 * OUT_F + fl * 4];
            acc0.x += v0 * x0.x; acc0.y += v0 * x0.y; acc0.z += v0 * x0.z; acc0.w += v0 * x0.w;
            acc1.x += v1 * x1.x; acc1.y += v1 * x1.y; acc1.z += v1 * x1.z; acc1.w += v1 * x1.w;
        }
    }
    float4 a;
    a.x = acc0.x + acc1.x; a.y = acc0.y + acc1.y;
    a.z = acc0.z + acc1.z; a.w = acc0.w + acc1.w;
    #pragma unroll
    for (int off = 16; off <= 32; off <<= 1) {
        a.x += __shfl_xor(a.x, off);
        a.y += __shfl_xor(a.y, off);
        a.z += __shfl_xor(a.z, off);
        a.w += __shfl_xor(a.w, off);
    }
    if (lane < 16) {
        float sg = sigma[wid];
        a.x *= sg; a.y *= sg; a.z *= sg; a.w *= sg;
        ((float4*)&y[(size_t)wid * OUT_F])[lane] = a;
    }
}

extern "C" void kernel_launch(void* const* d_in, const int* in_sizes, int n_in,
                              void* d_out, int out_size, void* d_ws, size_t ws_size,
                              hipStream_t stream) {
    const float* feat   = (const float*)d_in[0];
    const float* W      = (const float*)d_in[1];
    const float* attn_l = (const float*)d_in[2];
    const float* attn_r = (const float*)d_in[3];
    const int*   src    = (const int*)d_in[4];
    const int*   dst    = (const int*)d_in[5];
    float* out = (float*)d_out;

    char* p = (char*)d_ws;
    auto alloc = [&](size_t elems) {
        void* r = (void*)p;
        p += ((elems * 4 + 255) / 256) * 256;
        return r;
    };
    // region1: z0/zbuf (25.6 MB). Written by gemm, read hop1; hop2 out; hop3 in.
    float* zbuf = (float*)alloc((size_t)N_NODES * OUT_F);
    // region2 (25.6 MB): tmpd (12.8, scatter3->bucket) + tmps (1.6, scatter_src->
    // srccnt); both dead before hop1, where A (hop1 out / hop2 in) is born.
    char* r2 = (char*)alloc((size_t)N_NODES * OUT_F);
    int2*  tmpd = (int2*)r2;
    unsigned char* tmps = (unsigned char*)(r2 + (size_t)N_EDGES * 8);
    float* A    = (float*)r2;

    float2* csr      = (float2*)alloc((size_t)N_EDGES * 2);       // 12.8 MB
    int*    cntd     = (int*)   alloc((size_t)NBUCK * PB);        // 0.8 MB
    int*    cnts     = (int*)   alloc((size_t)NBUCK * PB);        // 0.8 MB
    int*    totd     = (int*)   alloc(NBUCK);
    int*    tots     = (int*)   alloc(NBUCK);
    int*    bstartd  = (int*)   alloc(NBUCK + 1);
    int*    bstarts  = (int*)   alloc(NBUCK + 1);
    int*    rowstart = (int*)   alloc(N_NODES + 1);
    float*  onorm    = (float*) alloc(N_NODES);
    float*  s12      = (float*) alloc(N_NODES);
    float*  s3       = (float*) alloc(N_NODES);
    float*  el       = (float*) alloc(N_NODES);
    float*  er       = (float*) alloc(N_NODES);

    const int NGB = (N_NODES + GM - 1) / GM;   // 391 gemm blocks

    k_hist       <<<PB,        256, 0, stream>>>(src, dst, cntd, cnts);
    k_colsum     <<<2 * NBUCK, 256, 0, stream>>>(cntd, cnts, totd, tots);
    k_bstart     <<<1,         512, 0, stream>>>(totd, tots, bstartd, bstarts);
    k_blockoff   <<<2 * NBUCK, 512, 0, stream>>>(bstartd, bstarts, cntd, cnts);
    k_scatter_src<<<PB,        256, 0, stream>>>(src, cnts, tmps);
    k_srccnt     <<<NBUCK,     256, 0, stream>>>(tmps, bstarts, onorm);
    k_gemm       <<<NGB,       256, 0, stream>>>(feat, W, attn_l, attn_r, onorm, zbuf, el, er);
    k_scatter3   <<<PB,        256, 0, stream>>>(src, dst, el, er, cntd, tmpd);
    k_bucket     <<<NBUCK,     256, 0, stream>>>(tmpd, bstartd, onorm, csr, rowstart, s12, s3);

    const int nb_spmm = (N_NODES + 3) / 4;
    k_spmm<<<nb_spmm, 256, 0, stream>>>(zbuf, rowstart, csr, s12, A);    // hop 1
    k_spmm<<<nb_spmm, 256, 0, stream>>>(A,    rowstart, csr, s12, zbuf); // hop 2
    k_spmm<<<nb_spmm, 256, 0, stream>>>(zbuf, rowstart, csr, s3,  out);  // hop 3
}

// Round 6
// 377.264 us; speedup vs baseline: 1.9154x; 1.0726x over previous
//
#include <hip/hip_runtime.h>
#include <math.h>

#define N_NODES 100000
#define N_EDGES 1600000
#define IN_F 128
#define OUT_F 64
#define NEG_SLOPE 0.2f

#define NBUCK 391          // ceil(N_NODES / 256): bucket = 256 consecutive node ids
#define PB 512             // edge-slice blocks for hist/scatter
#define EPB (N_EDGES / PB) // 3125 edges per slice

#define FS 132             // LDS row stride (uints) for packed feat/W tiles

typedef __attribute__((ext_vector_type(8))) short short8;
typedef __attribute__((ext_vector_type(4))) float f32x4;

__device__ __forceinline__ float wsum(float v) {
    #pragma unroll
    for (int off = 32; off; off >>= 1) v += __shfl_xor(v, off);
    return v;
}

// split f32 -> bf16 hi/lo packed in one uint: (hi16<<16)|lo16, x ~= hi + lo
__device__ __forceinline__ unsigned pack_bf(float f) {
    unsigned u  = __float_as_uint(f);
    unsigned hi = u & 0xffff0000u;
    float    lo = f - __uint_as_float(hi);
    return hi | (__float_as_uint(lo) >> 16);
}

__device__ __forceinline__ void unpack8(uint4 p0, uint4 p1, short8& hi, short8& lo) {
    hi[0] = (short)(p0.x >> 16); lo[0] = (short)(p0.x & 0xffffu);
    hi[1] = (short)(p0.y >> 16); lo[1] = (short)(p0.y & 0xffffu);
    hi[2] = (short)(p0.z >> 16); lo[2] = (short)(p0.z & 0xffffu);
    hi[3] = (short)(p0.w >> 16); lo[3] = (short)(p0.w & 0xffffu);
    hi[4] = (short)(p1.x >> 16); lo[4] = (short)(p1.x & 0xffffu);
    hi[5] = (short)(p1.y >> 16); lo[5] = (short)(p1.y & 0xffffu);
    hi[6] = (short)(p1.z >> 16); lo[6] = (short)(p1.z & 0xffffu);
    hi[7] = (short)(p1.w >> 16); lo[7] = (short)(p1.w & 0xffffu);
}

// ---------------- GEMM via split-bf16 MFMA: z0 = onorm*(feat@W^T), fused el/er ----
// Block = 64 nodes, 4 waves; wave = 16 nodes x 64 out-feats.
// D = Ahi*Bhi + Ahi*Blo + Alo*Bhi (f32 acc) ~ f32 GEMM to ~2^-16 rel.
__global__ __launch_bounds__(256) void k_gemm(
        const float* __restrict__ feat, const float* __restrict__ W,
        const float* __restrict__ attn_l, const float* __restrict__ attn_r,
        const float* __restrict__ onorm, float* __restrict__ z0,
        float* __restrict__ el, float* __restrict__ er) {
    __shared__ __align__(16) unsigned flds[64 * FS];   // 64 nodes x 128 k, packed
    __shared__ __align__(16) unsigned wlds[64 * FS];   // 64 outf x 128 k, packed
    int t = threadIdx.x;
    int n0 = blockIdx.x * 64;

    #pragma unroll
    for (int j = 0; j < 8; ++j) {              // 2048 float4-quads each for W, feat
        int idx = t + j * 256;
        int row = idx >> 5, k4 = (idx & 31) * 4;
        float4 wv = *(const float4*)&W[row * IN_F + k4];
        unsigned* wp = &wlds[row * FS + k4];
        wp[0] = pack_bf(wv.x); wp[1] = pack_bf(wv.y);
        wp[2] = pack_bf(wv.z); wp[3] = pack_bf(wv.w);
        int g = n0 + row;
        float4 fv = {0.f, 0.f, 0.f, 0.f};
        if (g < N_NODES) fv = *(const float4*)&feat[(size_t)g * IN_F + k4];
        unsigned* fp = &flds[row * FS + k4];
        fp[0] = pack_bf(fv.x); fp[1] = pack_bf(fv.y);
        fp[2] = pack_bf(fv.z); fp[3] = pack_bf(fv.w);
    }
    __syncthreads();

    int lane = t & 63, wv_ = t >> 6;
    int quad = lane >> 4, nl = lane & 15;
    int mrow = wv_ * 16 + nl;                  // A-operand node row for this lane

    f32x4 acc[4];
    #pragma unroll
    for (int nt = 0; nt < 4; ++nt) acc[nt] = (f32x4){0.f, 0.f, 0.f, 0.f};

    #pragma unroll
    for (int ks = 0; ks < 4; ++ks) {
        int ko = ks * 32 + quad * 8;
        const uint4* ap = (const uint4*)&flds[mrow * FS + ko];
        uint4 a0 = ap[0], a1 = ap[1];
        short8 ahi, alo; unpack8(a0, a1, ahi, alo);
        #pragma unroll
        for (int nt = 0; nt < 4; ++nt) {
            const uint4* bp = (const uint4*)&wlds[(nt * 16 + nl) * FS + ko];
            uint4 b0 = bp[0], b1 = bp[1];
            short8 bhi, blo; unpack8(b0, b1, bhi, blo);
            acc[nt] = __builtin_amdgcn_mfma_f32_16x16x32_bf16(ahi, bhi, acc[nt], 0, 0, 0);
            acc[nt] = __builtin_amdgcn_mfma_f32_16x16x32_bf16(ahi, blo, acc[nt], 0, 0, 0);
            acc[nt] = __builtin_amdgcn_mfma_f32_16x16x32_bf16(alo, bhi, acc[nt], 0, 0, 0);
        }
    }

    // C/D layout: col n = nt*16 + nl, row m (node within wave tile) = quad*4 + r
    float al4[4], ar4[4];
    #pragma unroll
    for (int nt = 0; nt < 4; ++nt) { al4[nt] = attn_l[nt * 16 + nl]; ar4[nt] = attn_r[nt * 16 + nl]; }
    float elp[4] = {0.f, 0.f, 0.f, 0.f}, erp[4] = {0.f, 0.f, 0.f, 0.f};
    #pragma unroll
    for (int nt = 0; nt < 4; ++nt)
        #pragma unroll
        for (int r = 0; r < 4; ++r) {
            elp[r] += acc[nt][r] * al4[nt];
            erp[r] += acc[nt][r] * ar4[nt];
        }
    #pragma unroll
    for (int off = 1; off <= 8; off <<= 1)
        #pragma unroll
        for (int r = 0; r < 4; ++r) {
            elp[r] += __shfl_xor(elp[r], off);
            erp[r] += __shfl_xor(erp[r], off);
        }
    int gbase = n0 + wv_ * 16 + quad * 4;
    if (nl == 0) {
        #pragma unroll
        for (int r = 0; r < 4; ++r) {
            int g = gbase + r;
            if (g < N_NODES) { el[g] = elp[r]; er[g] = erp[r]; }
        }
    }
    #pragma unroll
    for (int r = 0; r < 4; ++r) {
        int g = gbase + r;
        if (g < N_NODES) {
            float on = onorm[g];
            #pragma unroll
            for (int nt = 0; nt < 4; ++nt)
                z0[(size_t)g * OUT_F + nt * 16 + nl] = acc[nt][r] * on;
        }
    }
}

// ---------------- per-block bucket histograms (dst AND src), no global atomics ----
__global__ __launch_bounds__(256) void k_hist(
        const int* __restrict__ src, const int* __restrict__ dst,
        int* __restrict__ cntd, int* __restrict__ cnts) {
    __shared__ int hd[NBUCK], hs[NBUCK];
    int t = threadIdx.x, b = blockIdx.x;
    for (int k = t; k < NBUCK; k += 256) { hd[k] = 0; hs[k] = 0; }
    __syncthreads();
    int base = b * EPB;
    for (int i = t; i < EPB; i += 256) {
        atomicAdd(&hd[dst[base + i] >> 8], 1);   // LDS atomics (on-CU)
        atomicAdd(&hs[src[base + i] >> 8], 1);
    }
    __syncthreads();
    for (int k = t; k < NBUCK; k += 256) {
        cntd[k * PB + b] = hd[k];
        cnts[k * PB + b] = hs[k];
    }
}

// ---------------- bucket totals = column sums of count matrices -------------------
__global__ __launch_bounds__(256) void k_colsum(const int* __restrict__ cntd,
                                                const int* __restrict__ cnts,
                                                int* __restrict__ totd,
                                                int* __restrict__ tots) {
    __shared__ int s[256];
    int b = blockIdx.x, t = threadIdx.x;
    const int* m; int* o; int k;
    if (b < NBUCK) { m = cntd; o = totd; k = b; }
    else           { m = cnts; o = tots; k = b - NBUCK; }
    s[t] = m[k * PB + t] + m[k * PB + t + 256];
    __syncthreads();
    for (int d = 128; d; d >>= 1) { if (t < d) s[t] += s[t + d]; __syncthreads(); }
    if (t == 0) o[k] = s[0];
}

// ---------------- exclusive scans of bucket totals (both keys) --------------------
__global__ __launch_bounds__(512) void k_bstart(const int* __restrict__ totd,
                                                const int* __restrict__ tots,
                                                int* bstartd, int* bstarts) {
    __shared__ int s[512];
    int t = threadIdx.x;
    int v = (t < NBUCK) ? totd[t] : 0;
    s[t] = v; __syncthreads();
    for (int d = 1; d < 512; d <<= 1) { int a = (t >= d) ? s[t - d] : 0; __syncthreads(); s[t] += a; __syncthreads(); }
    if (t <= NBUCK) bstartd[t] = s[t] - v;
    __syncthreads();
    int v2 = (t < NBUCK) ? tots[t] : 0;
    s[t] = v2; __syncthreads();
    for (int d = 1; d < 512; d <<= 1) { int a = (t >= d) ? s[t - d] : 0; __syncthreads(); s[t] += a; __syncthreads(); }
    if (t <= NBUCK) bstarts[t] = s[t] - v2;
}

// ---------------- per-(bucket,block) offsets, in place, both matrices -------------
__global__ __launch_bounds__(512) void k_blockoff(const int* __restrict__ bstartd,
                                                  const int* __restrict__ bstarts,
                                                  int* cntd, int* cnts) {
    __shared__ int s[512];
    int b = blockIdx.x, t = threadIdx.x;
    int* m; const int* bs; int k;
    if (b < NBUCK) { m = cntd; bs = bstartd; k = b; }
    else           { m = cnts; bs = bstarts; k = b - NBUCK; }
    int c = m[k * PB + t];
    s[t] = c; __syncthreads();
    for (int d = 1; d < 512; d <<= 1) { int a = (t >= d) ? s[t - d] : 0; __syncthreads(); s[t] += a; __syncthreads(); }
    m[k * PB + t] = bs[k] + s[t] - c;
}

// ---------------- src-key scatter (bytes only; independent of el/er) --------------
__global__ __launch_bounds__(256) void k_scatter_src(
        const int* __restrict__ src, const int* __restrict__ offs,
        unsigned char* __restrict__ tmps) {
    __shared__ int lOffS[NBUCK], lFillS[NBUCK];
    int t = threadIdx.x, b = blockIdx.x;
    for (int k = t; k < NBUCK; k += 256) { lOffS[k] = offs[k * PB + b]; lFillS[k] = 0; }
    __syncthreads();
    int base = b * EPB;
    for (int i = t; i < EPB; i += 256) {
        int sN = src[base + i];
        int ks = sN >> 8;
        int rs = atomicAdd(&lFillS[ks], 1);       // LDS atomic
        tmps[lOffS[ks] + rs] = (unsigned char)(sN & 255);
    }
}

// ---------------- src-bucket count -> onorm, plain stores -------------------------
__global__ __launch_bounds__(256) void k_srccnt(
        const unsigned char* __restrict__ tmps, const int* __restrict__ bstarts,
        float* __restrict__ onorm) {
    __shared__ int cnt[256];
    int k = blockIdx.x, t = threadIdx.x;
    cnt[t] = 0; __syncthreads();
    int base = bstarts[k], end = bstarts[k + 1];
    for (int i = base + t; i < end; i += 256)
        atomicAdd(&cnt[tmps[i]], 1);
    __syncthreads();
    int idx = k * 256 + t;
    if (idx < N_NODES) onorm[idx] = rsqrtf((float)max(cnt[t], 1));
}

// ---------------- dst-key scatter: {src|dst_low, pexp} records --------------------
__global__ __launch_bounds__(256) void k_scatter3(
        const int* __restrict__ src, const int* __restrict__ dst,
        const float* __restrict__ el, const float* __restrict__ er,
        const int* __restrict__ offd, int2* __restrict__ tmpd) {
    __shared__ int lOffD[NBUCK], lFillD[NBUCK];
    int t = threadIdx.x, b = blockIdx.x;
    for (int k = t; k < NBUCK; k += 256) { lOffD[k] = offd[k * PB + b]; lFillD[k] = 0; }
    __syncthreads();
    int base = b * EPB;
    for (int i = t; i < EPB; i += 256) {
        int e = base + i;
        int sN = src[e], d = dst[e];
        float v = el[sN] + er[d];
        v = (v > 0.f) ? v : NEG_SLOPE * v;
        float pe = __expf(v);
        int kd = d >> 8;
        int rd = atomicAdd(&lFillD[kd], 1);       // LDS atomic
        int2 rec; rec.x = sN | ((d & 255) << 17); rec.y = __float_as_int(pe);
        tmpd[lOffD[kd] + rd] = rec;
    }
}

// ---------------- per-bucket fine sort -> CSR, rowstart, denom, scales ------------
__global__ __launch_bounds__(256) void k_bucket(
        const int2* __restrict__ tmp, const int* __restrict__ bstart,
        const float* __restrict__ onorm, float2* __restrict__ csr,
        int* __restrict__ rowstart, float* __restrict__ s12, float* __restrict__ s3) {
    __shared__ int   cs[256];
    __shared__ int   excl[256];
    __shared__ int   fill[256];
    __shared__ float dsum[256];
    int k = blockIdx.x, t = threadIdx.x;
    int base = bstart[k], end = bstart[k + 1];
    cs[t] = 0; fill[t] = 0; dsum[t] = 0.f;
    __syncthreads();
    for (int i = base + t; i < end; i += 256)
        atomicAdd(&cs[(tmp[i].x >> 17) & 255], 1);
    __syncthreads();
    int c = cs[t];
    for (int d = 1; d < 256; d <<= 1) {
        int a = (t >= d) ? cs[t - d] : 0;
        __syncthreads();
        cs[t] += a;
        __syncthreads();
    }
    excl[t] = cs[t] - c;
    __syncthreads();
    int idx = k * 256 + t;
    if (idx <= N_NODES) rowstart[idx] = base + excl[t];
    for (int i = base + t; i < end; i += 256) {
        int2 rec = tmp[i];
        int dlow = (rec.x >> 17) & 255;
        int r = atomicAdd(&fill[dlow], 1);
        float pe = __int_as_float(rec.y);
        float2 w;
        w.x = __int_as_float(rec.x & 131071);
        w.y = pe;
        csr[base + excl[dlow] + r] = w;
        atomicAdd(&dsum[dlow], pe);
    }
    __syncthreads();
    if (idx < N_NODES) {
        float inn = sqrtf((float)max(c, 1));
        float rs  = (c > 0) ? inn / dsum[t] : 0.f;
        s12[idx] = onorm[idx] * rs;
        s3[idx]  = rs;
    }
}

// ---------------- SpMM hop: y[d] = sigma[d] * sum_e pexp_e * x[col_e] -------------
__global__ __launch_bounds__(256) void k_spmm(
        const float* __restrict__ x, const int* __restrict__ rowstart,
        const float2* __restrict__ csr, const float* __restrict__ sigma,
        float* __restrict__ y) {
    int wid  = (blockIdx.x * 256 + threadIdx.x) >> 6;
    int lane = threadIdx.x & 63;
    if (wid >= N_NODES) return;
    int b = rowstart[wid], eend = rowstart[wid + 1];
    int g  = lane >> 4;          // edge group 0..3
    int fl = lane & 15;          // feature quad 0..15
    float4 acc0 = {0.f, 0.f, 0.f, 0.f};
    float4 acc1 = {0.f, 0.f, 0.f, 0.f};
    for (int i = b; i < eend; i += 64) {
        int j = i + lane;
        int c = 0; float v = 0.f;
        if (j < eend) { float2 w = csr[j]; c = __float_as_int(w.x); v = w.y; }
        int cnt = min(64, eend - i);
        for (int t = 0; t < cnt; t += 8) {
            int   c0 = __shfl(c, t + g),     c1 = __shfl(c, t + 4 + g);
            float v0 = __shfl(v, t + g),     v1 = __shfl(v, t + 4 + g);
            float4 x0 = *(const float4*)&x[(size_t)c0 * OUT_F + fl * 4];
            float4 x1 = *(const float4*)&x[(size_t)c1 * OUT_F + fl * 4];
            acc0.x += v0 * x0.x; acc0.y += v0 * x0.y; acc0.z += v0 * x0.z; acc0.w += v0 * x0.w;
            acc1.x += v1 * x1.x; acc1.y += v1 * x1.y; acc1.z += v1 * x1.z; acc1.w += v1 * x1.w;
        }
    }
    float4 a;
    a.x = acc0.x + acc1.x; a.y = acc0.y + acc1.y;
    a.z = acc0.z + acc1.z; a.w = acc0.w + acc1.w;
    #pragma unroll
    for (int off = 16; off <= 32; off <<= 1) {
        a.x += __shfl_xor(a.x, off);
        a.y += __shfl_xor(a.y, off);
        a.z += __shfl_xor(a.z, off);
        a.w += __shfl_xor(a.w, off);
    }
    if (lane < 16) {
        float sg = sigma[wid];
        a.x *= sg; a.y *= sg; a.z *= sg; a.w *= sg;
        ((float4*)&y[(size_t)wid * OUT_F])[lane] = a;
    }
}

extern "C" void kernel_launch(void* const* d_in, const int* in_sizes, int n_in,
                              void* d_out, int out_size, void* d_ws, size_t ws_size,
                              hipStream_t stream) {
    const float* feat   = (const float*)d_in[0];
    const float* W      = (const float*)d_in[1];
    const float* attn_l = (const float*)d_in[2];
    const float* attn_r = (const float*)d_in[3];
    const int*   src    = (const int*)d_in[4];
    const int*   dst    = (const int*)d_in[5];
    float* out = (float*)d_out;

    char* p = (char*)d_ws;
    auto alloc = [&](size_t elems) {
        void* r = (void*)p;
        p += ((elems * 4 + 255) / 256) * 256;
        return r;
    };
    // region1: z0/zbuf (25.6 MB). Written by gemm, read hop1; hop2 out; hop3 in.
    float* zbuf = (float*)alloc((size_t)N_NODES * OUT_F);
    // region2 (25.6 MB): tmpd (12.8, scatter3->bucket) + tmps (1.6, scatter_src->
    // srccnt); both dead before hop1, where A (hop1 out / hop2 in) is born.
    char* r2 = (char*)alloc((size_t)N_NODES * OUT_F);
    int2*  tmpd = (int2*)r2;
    unsigned char* tmps = (unsigned char*)(r2 + (size_t)N_EDGES * 8);
    float* A    = (float*)r2;

    float2* csr      = (float2*)alloc((size_t)N_EDGES * 2);       // 12.8 MB
    int*    cntd     = (int*)   alloc((size_t)NBUCK * PB);        // 0.8 MB
    int*    cnts     = (int*)   alloc((size_t)NBUCK * PB);        // 0.8 MB
    int*    totd     = (int*)   alloc(NBUCK);
    int*    tots     = (int*)   alloc(NBUCK);
    int*    bstartd  = (int*)   alloc(NBUCK + 1);
    int*    bstarts  = (int*)   alloc(NBUCK + 1);
    int*    rowstart = (int*)   alloc(N_NODES + 1);
    float*  onorm    = (float*) alloc(N_NODES);
    float*  s12      = (float*) alloc(N_NODES);
    float*  s3       = (float*) alloc(N_NODES);
    float*  el       = (float*) alloc(N_NODES);
    float*  er       = (float*) alloc(N_NODES);

    const int NGB = (N_NODES + 63) / 64;   // 1563 gemm blocks

    k_hist       <<<PB,        256, 0, stream>>>(src, dst, cntd, cnts);
    k_colsum     <<<2 * NBUCK, 256, 0, stream>>>(cntd, cnts, totd, tots);
    k_bstart     <<<1,         512, 0, stream>>>(totd, tots, bstartd, bstarts);
    k_blockoff   <<<2 * NBUCK, 512, 0, stream>>>(bstartd, bstarts, cntd, cnts);
    k_scatter_src<<<PB,        256, 0, stream>>>(src, cnts, tmps);
    k_srccnt     <<<NBUCK,     256, 0, stream>>>(tmps, bstarts, onorm);
    k_gemm       <<<NGB,       256, 0, stream>>>(feat, W, attn_l, attn_r, onorm, zbuf, el, er);
    k_scatter3   <<<PB,        256, 0, stream>>>(src, dst, el, er, cntd, tmpd);
    k_bucket     <<<NBUCK,     256, 0, stream>>>(tmpd, bstartd, onorm, csr, rowstart, s12, s3);

    const int nb_spmm = (N_NODES + 3) / 4;
    k_spmm<<<nb_spmm, 256, 0, stream>>>(zbuf, rowstart, csr, s12, A);    // hop 1
    k_spmm<<<nb_spmm, 256, 0, stream>>>(A,    rowstart, csr, s12, zbuf); // hop 2
    k_spmm<<<nb_spmm, 256, 0, stream>>>(zbuf, rowstart, csr, s3,  out);  // hop 3
}